// Round 8
// baseline (2093.103 us; speedup 1.0000x reference)
//
#include <hip/hip_runtime.h>

// EGKN: E(n) graph kernel network.
#define NN 10000      // nodes
#define NE 300000     // edges
#define DEPTH 4

typedef unsigned int   u32;
typedef unsigned short u16;
typedef unsigned char  u8;

typedef _Float16 half8  __attribute__((ext_vector_type(8)));
typedef float  floatx16 __attribute__((ext_vector_type(16)));

// fp16 encode/decode via hardware v_cvt (with saturation on encode)
__device__ __forceinline__ u32 f2h(float f) {
    f = fminf(fmaxf(f, -60000.f), 60000.f);
    _Float16 h = (_Float16)f;
    return (u32)__builtin_bit_cast(u16, h);
}
__device__ __forceinline__ float h2f(u16 b) {
    return (float)__builtin_bit_cast(_Float16, b);
}

// ---------------------------------------------------------------------------
__global__ void sentinel_kernel(float* out, int n, float val) {
    int i = blockIdx.x * 256 + threadIdx.x;
    if (i < n) out[i] = val;
}

// ---------------------------------------------------------------------------
// edge_index dtype normalization (int64 vs int32)
// ---------------------------------------------------------------------------
__global__ void detect_idx_kernel(const int* __restrict__ ei, int* __restrict__ flag) {
    __shared__ int nz;
    if (threadIdx.x == 0) nz = 0;
    __syncthreads();
    if (ei[threadIdx.x * 2 + 1] != 0) atomicAdd(&nz, 1);
    __syncthreads();
    if (threadIdx.x == 0) *flag = (nz == 0) ? 1 : 0;   // 1 => int64
}

__global__ __launch_bounds__(256) void convert_idx_kernel(
    const int* __restrict__ ei, const int* __restrict__ flag,
    int* __restrict__ ridx, int* __restrict__ cidx)
{
    int e = blockIdx.x * 256 + threadIdx.x;
    if (e >= 2 * NE) return;
    const int is64 = *flag;
    int v = is64 ? ei[2 * e] : ei[e];
    if (e < NE) ridx[e] = v; else cidx[e - NE] = v;
}

// ---------------------------------------------------------------------------
// init: h = x @ fc1_w + fc1_b   [NN,32];  coord = coords_init copy
// ---------------------------------------------------------------------------
__global__ __launch_bounds__(256) void init_nodes_kernel(
    const float* __restrict__ x, const float* __restrict__ fc1w,
    const float* __restrict__ fc1b, const float* __restrict__ ci,
    float* __restrict__ h, float* __restrict__ coord)
{
    int idx = blockIdx.x * 256 + threadIdx.x;
    if (idx < NN * 32) {
        int v = idx >> 5, f = idx & 31;
        float acc = fc1b[f];
#pragma unroll
        for (int i = 0; i < 3; i++) acc += x[v * 3 + i] * fc1w[i * 32 + f];
        h[idx] = acc;
    }
    if (idx < NN * 3) coord[idx] = ci[idx];
}

// ---------------------------------------------------------------------------
// CSR-by-col build: counts, scan, scatter
// ---------------------------------------------------------------------------
__global__ __launch_bounds__(256) void count_kernel(
    const int* __restrict__ ridx, const int* __restrict__ cidx,
    int* __restrict__ rowcnt, int* __restrict__ colcnt)
{
    int e = blockIdx.x * 256 + threadIdx.x;
    if (e < NE) { atomicAdd(&rowcnt[ridx[e]], 1); atomicAdd(&colcnt[cidx[e]], 1); }
}

__global__ void scan_kernel(const int* __restrict__ colcnt, const int* __restrict__ rowcnt,
                            int* __restrict__ cstart, int* __restrict__ cnext,
                            float* __restrict__ invc)
{
    __shared__ int part[256];
    const int t = threadIdx.x;
    int sum = 0;
    for (int i = 0; i < 40; i++) { int v = t * 40 + i; if (v < NN) sum += colcnt[v]; }
    part[t] = sum;
    __syncthreads();
    if (t == 0) {
        int run = 0;
        for (int i = 0; i < 256; i++) { int tmp = part[i]; part[i] = run; run += tmp; }
    }
    __syncthreads();
    int run = part[t];
    for (int i = 0; i < 40; i++) {
        int v = t * 40 + i;
        if (v < NN) { cstart[v] = run; cnext[v] = run; run += colcnt[v]; }
    }
    if (t == 255) cstart[NN] = run;
    for (int v = t; v < NN; v += 256) invc[v] = 1.0f / fmaxf((float)rowcnt[v], 1.0f);
}

__global__ __launch_bounds__(256) void scatter_kernel(
    const int* __restrict__ cidx, int* __restrict__ cnext, int* __restrict__ elist)
{
    int e = blockIdx.x * 256 + threadIdx.x;
    if (e < NE) { int pos = atomicAdd(&cnext[cidx[e]], 1); elist[pos] = e; }
}

// ---------------------------------------------------------------------------
// w2 -> fp16 MFMA B-fragment pack: w2h[((c*8+s)*64+l)*8+j] = w2[k][col],
// k = s*16+(l>>5)*8+j, col = c*32+(l&31).  (one-time, 64 KB)
// ---------------------------------------------------------------------------
__global__ __launch_bounds__(256) void w2pack_kernel(
    const float* __restrict__ w2, u16* __restrict__ w2h)
{
    const int slot = blockIdx.x * 256 + threadIdx.x;    // 0..4095
    const int c = slot >> 9, s = (slot >> 6) & 7, l = slot & 63;
    const int li = l & 31, hf = l >> 5;
    const int k0 = s * 16 + hf * 8, col = c * 32 + li;
    u32 pk[8];
#pragma unroll
    for (int j = 0; j < 8; j++) pk[j] = f2h(w2[(size_t)(k0 + j) * 256 + col]);
    uint4 o;
    o.x = pk[0] | (pk[1] << 16);
    o.y = pk[2] | (pk[3] << 16);
    o.z = pk[4] | (pk[5] << 16);
    o.w = pk[6] | (pk[7] << 16);
    *(uint4*)&w2h[(size_t)slot * 8] = o;
}

// ---------------------------------------------------------------------------
// k2 MLP: edge_attr[6] -> 128 -> 256 (relu both). 32 edges/block.
// Layer 1 (VALU) writes k1 straight into fp16 A-fragment order in LDS;
// layer 2 is 8 MFMA steps per col-tile (4 waves x 2 tiles).
// fk2=0: fp16 [e][256].  fk2=1: uint8 [e][256] + per-edge scale k2s[e].
// ---------------------------------------------------------------------------
__global__ __launch_bounds__(256) void mlp_k2_kernel(
    const float* __restrict__ ea,
    const float* __restrict__ w1, const float* __restrict__ b1,
    const u16* __restrict__ w2h, const float* __restrict__ b2,
    u8* __restrict__ k2base, float* __restrict__ k2s, int fk2)
{
    __shared__ __align__(16) float ea_s[32 * 6];
    __shared__ __align__(16) u16   k1f[4096];          // A-frags: [s][lane][j]
    __shared__ __align__(16) float M_s[32 * 260];      // [e][c], padded
    const int t  = threadIdx.x;
    const int e0 = blockIdx.x * 32;

    for (int idx = t; idx < 192; idx += 256)
        ea_s[idx] = ea[(size_t)e0 * 6 + idx];
    __syncthreads();

    // layer 1: [32,6]@[6,128] relu -> fp16 fragments
    for (int slot = t; slot < 512; slot += 256) {
        const int s  = slot >> 6;
        const int l  = slot & 63;
        const int li = l & 31, hf = l >> 5;
        const int k0 = s * 16 + hf * 8;
        float acc[8];
        {
            const float4 ba = *(const float4*)&b1[k0];
            const float4 bb = *(const float4*)&b1[k0 + 4];
            acc[0] = ba.x; acc[1] = ba.y; acc[2] = ba.z; acc[3] = ba.w;
            acc[4] = bb.x; acc[5] = bb.y; acc[6] = bb.z; acc[7] = bb.w;
        }
#pragma unroll
        for (int i = 0; i < 6; i++) {
            const float ev = ea_s[li * 6 + i];
            const float4 wa = *(const float4*)&w1[i * 128 + k0];
            const float4 wb = *(const float4*)&w1[i * 128 + k0 + 4];
            acc[0] += ev * wa.x; acc[1] += ev * wa.y;
            acc[2] += ev * wa.z; acc[3] += ev * wa.w;
            acc[4] += ev * wb.x; acc[5] += ev * wb.y;
            acc[6] += ev * wb.z; acc[7] += ev * wb.w;
        }
        uint4 o;
        o.x = f2h(fmaxf(acc[0], 0.f)) | (f2h(fmaxf(acc[1], 0.f)) << 16);
        o.y = f2h(fmaxf(acc[2], 0.f)) | (f2h(fmaxf(acc[3], 0.f)) << 16);
        o.z = f2h(fmaxf(acc[4], 0.f)) | (f2h(fmaxf(acc[5], 0.f)) << 16);
        o.w = f2h(fmaxf(acc[6], 0.f)) | (f2h(fmaxf(acc[7], 0.f)) << 16);
        *(uint4*)&k1f[slot * 8] = o;
    }
    __syncthreads();

    // layer 2: [32,128]@[128,256] via mfma_32x32x16_f16
    {
        const int w  = t >> 6, l = t & 63;
        const int li = l & 31, hf = l >> 5;
#pragma unroll
        for (int ct = 0; ct < 2; ct++) {
            const int c = w * 2 + ct;
            floatx16 acc;
#pragma unroll
            for (int r = 0; r < 16; r++) acc[r] = 0.f;
#pragma unroll
            for (int s = 0; s < 8; s++) {
                const half8 a = __builtin_bit_cast(half8,
                    *(const uint4*)&k1f[(s * 64 + l) * 8]);
                const half8 b = __builtin_bit_cast(half8,
                    *(const uint4*)&w2h[(((size_t)c * 8 + s) * 64 + l) * 8]);
                acc = __builtin_amdgcn_mfma_f32_32x32x16_f16(a, b, acc, 0, 0, 0);
            }
            const float bb = b2[c * 32 + li];
#pragma unroll
            for (int r = 0; r < 16; r++) {
                const int e = (r & 3) + 8 * (r >> 2) + 4 * hf;
                M_s[e * 260 + c * 32 + li] = fmaxf(acc[r] + bb, 0.f);
            }
        }
    }
    __syncthreads();

    // store k2: thread t -> edge el=t>>3, col-chunk q=t&7 (32 cols each)
    {
        const int el = t >> 3, q = t & 7;
        const size_t eglob = (size_t)e0 + el;
        if (fk2 == 0) {
            u16* outp = (u16*)k2base + eglob * 256 + q * 32;
#pragma unroll
            for (int u = 0; u < 8; u += 2) {
                float4 a = *(float4*)&M_s[el * 260 + q * 32 + u * 4];
                float4 b = *(float4*)&M_s[el * 260 + q * 32 + u * 4 + 4];
                uint4 o;
                o.x = f2h(a.x) | (f2h(a.y) << 16);
                o.y = f2h(a.z) | (f2h(a.w) << 16);
                o.z = f2h(b.x) | (f2h(b.y) << 16);
                o.w = f2h(b.z) | (f2h(b.w) << 16);
                *(uint4*)(outp + u * 4) = o;
            }
        } else {
            // per-edge max over the 8 lanes covering this edge
            float mx = 0.f;
#pragma unroll
            for (int u = 0; u < 32; u++) mx = fmaxf(mx, M_s[el * 260 + q * 32 + u]);
            mx = fmaxf(mx, __shfl_xor(mx, 1, 8));
            mx = fmaxf(mx, __shfl_xor(mx, 2, 8));
            mx = fmaxf(mx, __shfl_xor(mx, 4, 8));
            const float sc  = mx / 255.f;
            const float inv = (mx > 0.f) ? 255.f / mx : 0.f;
            if (q == 0) k2s[eglob] = sc;
            u8* outp = k2base + eglob * 256 + q * 32;
            u32 w[8];
#pragma unroll
            for (int u = 0; u < 8; u++) {
                float4 a = *(float4*)&M_s[el * 260 + q * 32 + u * 4];
                u32 q0 = (u32)fminf(rintf(a.x * inv), 255.f);
                u32 q1 = (u32)fminf(rintf(a.y * inv), 255.f);
                u32 q2 = (u32)fminf(rintf(a.z * inv), 255.f);
                u32 q3 = (u32)fminf(rintf(a.w * inv), 255.f);
                w[u] = q0 | (q1 << 8) | (q2 << 16) | (q3 << 24);
            }
            *(uint4*)outp        = make_uint4(w[0], w[1], w[2], w[3]);
            *(uint4*)(outp + 16) = make_uint4(w[4], w[5], w[6], w[7]);
        }
    }
}

// ---------------------------------------------------------------------------
// Bvec[v][i] = sum_j b3[i*32+j] * h[v][j]
// ---------------------------------------------------------------------------
__global__ __launch_bounds__(256) void bvec_kernel(
    const float* __restrict__ h, const float* __restrict__ b3, float* __restrict__ bvec)
{
    int idx = blockIdx.x * 256 + threadIdx.x;
    if (idx >= NN * 32) return;
    int v = idx >> 5, i = idx & 31;
    const float* hp = &h[(size_t)v * 32];
    const float* bp = &b3[i * 32];
    float acc = 0.f;
#pragma unroll
    for (int c = 0; c < 8; c++) {
        float4 hv = *(const float4*)&hp[c * 4];
        float4 bv = *(const float4*)&bp[c * 4];
        acc += hv.x * bv.x + hv.y * bv.y + hv.z * bv.z + hv.w * bv.w;
    }
    bvec[idx] = acc;
}

// ---------------------------------------------------------------------------
// G in MFMA-B-fragment order, fp16 (u16 offset o = s*512 + lane*8 + j holds
// G[k=s*16+(lane>>5)*8+j][i=lane&31]).  2 weight rows per thread; h read via
// WAVE-UNIFORM global loads (scalar pipe / constant cache — no LDS, no VALU
// load overhead; the round-7 4-row version hit a 256-VGPR occupancy cliff).
// Grid: (ceil(NN/128), 16).
// ---------------------------------------------------------------------------
__global__ __launch_bounds__(256, 4) void g_kernel(
    const float* __restrict__ h, const float* __restrict__ w3,
    u16* __restrict__ Gg)
{
    const int t  = threadIdx.x;
    const int v0 = blockIdx.x * 128;

    const int by    = blockIdx.y;        // step s, 0..15
    const int lane  = t >> 2;            // 0..63
    const int i     = lane & 31;
    const int halfk = lane >> 5;
    const int j0    = (t & 3) * 2;
    const int k0    = by * 16 + halfk * 8 + j0;

    float w0[32], w1[32];
    {
        const float* wp0 = &w3[(size_t)k0 * 1024 + (size_t)i * 32];
        const float* wp1 = wp0 + 1024;
#pragma unroll
        for (int c = 0; c < 8; c++) {
            float4 a = *(const float4*)&wp0[c * 4];
            w0[c * 4] = a.x; w0[c * 4 + 1] = a.y; w0[c * 4 + 2] = a.z; w0[c * 4 + 3] = a.w;
            float4 b = *(const float4*)&wp1[c * 4];
            w1[c * 4] = b.x; w1[c * 4 + 1] = b.y; w1[c * 4 + 2] = b.z; w1[c * 4 + 3] = b.w;
        }
    }
    const int vmax = min(128, NN - v0);
    u32* outp = (u32*)Gg;
#pragma unroll 2
    for (int v = 0; v < vmax; v++) {
        const float* hp = &h[(size_t)(v0 + v) * 32];   // wave-uniform address
        float a0 = 0.f, a1 = 0.f;
#pragma unroll
        for (int c = 0; c < 8; c++) {
            const float4 hv = *(const float4*)&hp[c * 4];
            a0 += hv.x * w0[c*4] + hv.y * w0[c*4+1] + hv.z * w0[c*4+2] + hv.w * w0[c*4+3];
            a1 += hv.x * w1[c*4] + hv.y * w1[c*4+1] + hv.z * w1[c*4+2] + hv.w * w1[c*4+3];
        }
        outp[(size_t)(v0 + v) * 4096 + by * 256 + t] = f2h(a0) | (f2h(a1) << 16);
    }
}

// ---------------------------------------------------------------------------
// MFMA edge pass. One wave64 per col-node n; 4 waves/block (independent).
// C/D layout: col = lane&31, row = (reg&3)+8*(reg>>2)+4*(lane>>5).
// ---------------------------------------------------------------------------
__global__ __launch_bounds__(256) void edge_kernel(
    const int* __restrict__ cstart, const int* __restrict__ elist,
    const int* __restrict__ ridx, const u8* __restrict__ k2base,
    const float* __restrict__ k2s, const u16* __restrict__ Gg,
    const float* __restrict__ coord,
    const float* __restrict__ cm1w, const float* __restrict__ cm1b,
    const float* __restrict__ cm2w, const float* __restrict__ cm2b,
    const float* __restrict__ bvec, float* __restrict__ agg,
    float* __restrict__ dco, int fk2)
{
    const int t    = threadIdx.x;
    const int w    = t >> 6;         // wave in block
    const int l    = t & 63;         // lane
    const int li   = l & 31;         // column index / lane-in-half
    const int half = l >> 5;

    __shared__ __align__(16) float Mlds_all[4][32 * 36];
    float* Mlds = Mlds_all[w];

    // cm1 B-fragments + cm2 (node-independent)
    half8 cmb[2];
#pragma unroll
    for (int s2 = 0; s2 < 2; s2++)
#pragma unroll
        for (int j = 0; j < 8; j++)
            cmb[s2][j] = (_Float16)cm1w[(s2 * 16 + half * 8 + j) * 32 + li];
    const float cm1bq = cm1b[li];
    const float cm2q  = cm2w[li];
    const float cm2b0 = cm2b[0];

    const int n = blockIdx.x * 4 + w;
    if (n >= NN) return;
    const int s0  = cstart[n];
    const int deg = cstart[n + 1] - s0;
    if (deg == 0) return;

    const float bv  = bvec[n * 32 + li];
    const float con = (li < 3) ? coord[(size_t)n * 3 + li] : 0.f;
    const u16* Gn = Gg + (size_t)n * 8192;

    for (int base = 0; base < deg; base += 32) {
        const int mye   = base + li;
        const int valid = (mye < deg) ? 1 : 0;
        const int eid   = valid ? elist[s0 + mye] : 0;
        const int rowv  = valid ? ridx[eid] : 0;

        floatx16 acc;
#pragma unroll
        for (int r = 0; r < 16; r++) acc[r] = bv;

        if (fk2 == 1) {
            const float se = valid ? k2s[eid] : 0.f;
            const u8* k2row = k2base + (size_t)eid * 256 + half * 8;
#pragma unroll
            for (int s = 0; s < 16; s++) {
                const uint2 wd = *(const uint2*)(k2row + s * 16);
                half8 a;
#pragma unroll
                for (int j = 0; j < 4; j++) {
                    a[j]     = (_Float16)((float)((wd.x >> (8 * j)) & 0xffu) * se);
                    a[4 + j] = (_Float16)((float)((wd.y >> (8 * j)) & 0xffu) * se);
                }
                const half8 b = __builtin_bit_cast(half8,
                    *(const uint4*)(Gn + s * 512 + l * 8));
                acc = __builtin_amdgcn_mfma_f32_32x32x16_f16(a, b, acc, 0, 0, 0);
            }
        } else {
            const u16* k2row = (const u16*)k2base + (size_t)eid * 256 + half * 8;
#pragma unroll
            for (int s = 0; s < 16; s++) {
                const half8 a = __builtin_bit_cast(half8, *(const uint4*)(k2row + s * 16));
                const half8 b = __builtin_bit_cast(half8,
                    *(const uint4*)(Gn + s * 512 + l * 8));
                acc = __builtin_amdgcn_mfma_f32_32x32x16_f16(a, b, acc, 0, 0, 0);
            }
        }

        // M -> LDS (fp32, stride 36 for bank spread / 16B alignment)
#pragma unroll
        for (int r = 0; r < 16; r++) {
            const int e = (r & 3) + 8 * (r >> 2) + 4 * half;
            Mlds[e * 36 + li] = acc[r];
        }
        asm volatile("s_waitcnt lgkmcnt(0)" ::: "memory");

        // T = cm1b + M @ cm1
        floatx16 acc2;
#pragma unroll
        for (int r = 0; r < 16; r++) acc2[r] = cm1bq;
#pragma unroll
        for (int s2 = 0; s2 < 2; s2++) {
            const float* mp = &Mlds[li * 36 + s2 * 16 + half * 8];
            const float4 m0 = *(const float4*)mp;
            const float4 m1 = *(const float4*)(mp + 4);
            half8 a;
            a[0] = (_Float16)m0.x; a[1] = (_Float16)m0.y;
            a[2] = (_Float16)m0.z; a[3] = (_Float16)m0.w;
            a[4] = (_Float16)m1.x; a[5] = (_Float16)m1.y;
            a[6] = (_Float16)m1.z; a[7] = (_Float16)m1.w;
            acc2 = __builtin_amdgcn_mfma_f32_32x32x16_f16(a, cmb[s2], acc2, 0, 0, 0);
        }

        // epilogue: per C-reg r -> edge e; we-reduction + atomics
#pragma unroll
        for (int r = 0; r < 16; r++) {
            const int e  = (r & 3) + 8 * (r >> 2) + 4 * half;
            const int vr = __shfl(valid, e, 32);
            const int rr = __shfl(rowv, e, 32);
            float part = fmaxf(acc2[r], 0.f) * cm2q;
            part += __shfl_xor(part, 1, 32);
            part += __shfl_xor(part, 2, 32);
            part += __shfl_xor(part, 4, 32);
            part += __shfl_xor(part, 8, 32);
            part += __shfl_xor(part, 16, 32);
            const float wer = part + cm2b0;
            if (vr) {
                atomicAdd(&agg[(size_t)rr * 32 + li], acc[r]);
                if (li < 3) {
                    const float d = coord[(size_t)rr * 3 + li] - con;
                    atomicAdd(&dco[(size_t)rr * 3 + li], d * wer);
                }
            }
        }
    }
}

// ---------------------------------------------------------------------------
__global__ __launch_bounds__(256) void node_update_kernel(
    float* __restrict__ h, float* __restrict__ agg,
    float* __restrict__ coord, float* __restrict__ dco,
    const float* __restrict__ invc)
{
    int idx = blockIdx.x * 256 + threadIdx.x;
    if (idx < NN * 32) {
        int v = idx >> 5;
        h[idx] = fmaxf(h[idx] + agg[idx] * invc[v], 0.f);
        agg[idx] = 0.f;
    }
    if (idx < NN * 3) {
        coord[idx] += dco[idx] * invc[idx / 3];
        dco[idx] = 0.f;
    }
}

// ---------------------------------------------------------------------------
__global__ __launch_bounds__(256) void final_kernel(
    const float* __restrict__ h, const float* __restrict__ coord,
    const float* __restrict__ wa, const float* __restrict__ ba,
    const float* __restrict__ wb, const float* __restrict__ bb,
    float* __restrict__ out)
{
    const int lane = threadIdx.x & 63;
    const int v = blockIdx.x * 4 + (threadIdx.x >> 6);
    if (v >= NN) return;
    const float hreg = (lane < 32) ? h[(size_t)v * 32 + lane] : 0.f;
    float acc = ba[lane];
#pragma unroll
    for (int f = 0; f < 32; f++) acc += __shfl(hreg, f, 64) * wa[f * 64 + lane];
    float part = fmaxf(acc, 0.f) * wb[lane];
#pragma unroll
    for (int off = 32; off >= 1; off >>= 1) part += __shfl_xor(part, off, 64);
    if (lane == 0) out[v] = part + bb[0];
    if (lane < 3) out[NN + (size_t)v * 3 + lane] = coord[(size_t)v * 3 + lane];
}

// ---------------------------------------------------------------------------
extern "C" void kernel_launch(void* const* d_in, const int* in_sizes, int n_in,
                              void* d_out, int out_size, void* d_ws, size_t ws_size,
                              hipStream_t stream)
{
    const float* x    = (const float*)d_in[0];
    const int*   ei   = (const int*)d_in[1];
    const float* ea   = (const float*)d_in[2];
    const float* ci   = (const float*)d_in[3];
    const float* fc1w = (const float*)d_in[4];
    const float* fc1b = (const float*)d_in[5];
    const float* k1w  = (const float*)d_in[6];
    const float* k1b  = (const float*)d_in[7];
    const float* k2w  = (const float*)d_in[8];
    const float* k2b  = (const float*)d_in[9];
    const float* k3w  = (const float*)d_in[10];
    const float* k3b  = (const float*)d_in[11];
    const float* cm1w = (const float*)d_in[12];
    const float* cm1b = (const float*)d_in[13];
    const float* cm2w = (const float*)d_in[14];
    const float* cm2b = (const float*)d_in[15];
    const float* f2aw = (const float*)d_in[16];
    const float* f2ab = (const float*)d_in[17];
    const float* f2bw = (const float*)d_in[18];
    const float* f2bb = (const float*)d_in[19];

    // ---- workspace carve; tiers: A=(2) fp16 k2, B=(1) u8 k2. G always fp16.
    size_t o_k2, o_k2s, o_G, o_h, o_agg, o_bv, o_coord, o_dco, o_invc, o_rc,
           o_cc, o_cs, o_cn, o_el, o_ri, o_ci, o_w2h;
#define ALGN(v) (((v) + 255) & ~(size_t)255)
    auto carve = [&](size_t k2es) -> size_t {
        size_t o = 0;
        o_k2   = o; o += ALGN((size_t)NE * 256 * k2es);
        o_k2s  = o; o += ALGN((size_t)NE * 4);
        o_G    = o; o += ALGN((size_t)NN * 8192 * 2);
        o_h    = o; o += ALGN((size_t)NN * 32 * 4);
        o_agg  = o; o += ALGN((size_t)NN * 32 * 4);
        o_bv   = o; o += ALGN((size_t)NN * 32 * 4);
        o_coord= o; o += ALGN((size_t)NN * 3 * 4);
        o_dco  = o; o += ALGN((size_t)NN * 3 * 4);
        o_invc = o; o += ALGN((size_t)NN * 4);
        o_rc   = o; o += ALGN((size_t)NN * 4);
        o_cc   = o; o += ALGN((size_t)NN * 4);
        o_cs   = o; o += ALGN((size_t)(NN + 1) * 4);
        o_cn   = o; o += ALGN((size_t)NN * 4);
        o_el   = o; o += ALGN((size_t)NE * 4);
        o_ri   = o; o += ALGN((size_t)NE * 4);
        o_ci   = o; o += ALGN((size_t)NE * 4);
        o_w2h  = o; o += ALGN((size_t)128 * 256 * 2);
        return o;
    };
    int fk2;
    if      (ws_size >= carve(2)) { fk2 = 0; carve(2); }  // ~328 MB
    else if (ws_size >= carve(1)) { fk2 = 1; carve(1); }  // ~251 MB
    else {
        sentinel_kernel<<<(NN * 4 + 255) / 256, 256, 0, stream>>>((float*)d_out, NN * 4, 1.0e6f);
        return;
    }

    char* wsb = (char*)d_ws;
    u8*    k2g   = (u8*)(wsb + o_k2);
    float* k2s   = (float*)(wsb + o_k2s);
    u16*   Gg    = (u16*)(wsb + o_G);
    float* h     = (float*)(wsb + o_h);
    float* agg   = (float*)(wsb + o_agg);
    float* bvec  = (float*)(wsb + o_bv);
    float* coord = (float*)(wsb + o_coord);
    float* dco   = (float*)(wsb + o_dco);
    float* invc  = (float*)(wsb + o_invc);
    int*   rowcnt= (int*)(wsb + o_rc);
    int*   colcnt= (int*)(wsb + o_cc);
    int*   cstart= (int*)(wsb + o_cs);
    int*   cnext = (int*)(wsb + o_cn);
    int*   elist = (int*)(wsb + o_el);
    int*   ridx  = (int*)(wsb + o_ri);
    int*   cidx  = (int*)(wsb + o_ci);
    u16*   w2h   = (u16*)(wsb + o_w2h);

    hipMemsetAsync(agg,    0, (size_t)NN * 32 * 4, stream);
    hipMemsetAsync(dco,    0, (size_t)NN * 3 * 4, stream);
    hipMemsetAsync(rowcnt, 0, (size_t)NN * 4, stream);
    hipMemsetAsync(colcnt, 0, (size_t)NN * 4, stream);

    detect_idx_kernel<<<1, 256, 0, stream>>>(ei, cnext);   // cnext[0] as flag temp
    convert_idx_kernel<<<(2 * NE + 255) / 256, 256, 0, stream>>>(ei, cnext, ridx, cidx);
    init_nodes_kernel<<<(NN * 32 + 255) / 256, 256, 0, stream>>>(x, fc1w, fc1b, ci, h, coord);
    count_kernel<<<(NE + 255) / 256, 256, 0, stream>>>(ridx, cidx, rowcnt, colcnt);
    scan_kernel<<<1, 256, 0, stream>>>(colcnt, rowcnt, cstart, cnext, invc);
    scatter_kernel<<<(NE + 255) / 256, 256, 0, stream>>>(cidx, cnext, elist);
    w2pack_kernel<<<16, 256, 0, stream>>>(k2w, w2h);
    mlp_k2_kernel<<<NE / 32, 256, 0, stream>>>(ea, k1w, k1b, w2h, k2b, k2g, k2s, fk2);

    const dim3 ggrid((NN + 127) / 128, 16);
    for (int l = 0; l < DEPTH; l++) {
        bvec_kernel<<<(NN * 32 + 255) / 256, 256, 0, stream>>>(h, k3b, bvec);
        g_kernel<<<ggrid, 256, 0, stream>>>(h, k3w, Gg);
        edge_kernel<<<(NN + 3) / 4, 256, 0, stream>>>(cstart, elist, ridx, k2g, k2s,
                                                      Gg, coord, cm1w, cm1b, cm2w, cm2b,
                                                      bvec, agg, dco, fk2);
        node_update_kernel<<<(NN * 32 + 255) / 256, 256, 0, stream>>>(h, agg, coord, dco, invc);
    }
    final_kernel<<<(NN + 3) / 4, 256, 0, stream>>>(h, coord, f2aw, f2ab, f2bw, f2bb,
                                                   (float*)d_out);
}

// Round 9
// 1068.834 us; speedup vs baseline: 1.9583x; 1.9583x over previous
//
#include <hip/hip_runtime.h>

// EGKN: E(n) graph kernel network.
#define NN 10000      // nodes
#define NE 300000     // edges
#define DEPTH 4

typedef unsigned int   u32;
typedef unsigned short u16;
typedef unsigned char  u8;

typedef _Float16 half8  __attribute__((ext_vector_type(8)));
typedef _Float16 half2t __attribute__((ext_vector_type(2)));
typedef float  floatx16 __attribute__((ext_vector_type(16)));

// fp16 encode/decode via hardware v_cvt (with saturation on encode)
__device__ __forceinline__ u32 f2h(float f) {
    f = fminf(fmaxf(f, -60000.f), 60000.f);
    _Float16 h = (_Float16)f;
    return (u32)__builtin_bit_cast(u16, h);
}
__device__ __forceinline__ float h2f(u16 b) {
    return (float)__builtin_bit_cast(_Float16, b);
}

// ---------------------------------------------------------------------------
__global__ void sentinel_kernel(float* out, int n, float val) {
    int i = blockIdx.x * 256 + threadIdx.x;
    if (i < n) out[i] = val;
}

// ---------------------------------------------------------------------------
// edge_index dtype normalization (int64 vs int32)
// ---------------------------------------------------------------------------
__global__ void detect_idx_kernel(const int* __restrict__ ei, int* __restrict__ flag) {
    __shared__ int nz;
    if (threadIdx.x == 0) nz = 0;
    __syncthreads();
    if (ei[threadIdx.x * 2 + 1] != 0) atomicAdd(&nz, 1);
    __syncthreads();
    if (threadIdx.x == 0) *flag = (nz == 0) ? 1 : 0;   // 1 => int64
}

__global__ __launch_bounds__(256) void convert_idx_kernel(
    const int* __restrict__ ei, const int* __restrict__ flag,
    int* __restrict__ ridx, int* __restrict__ cidx)
{
    int e = blockIdx.x * 256 + threadIdx.x;
    if (e >= 2 * NE) return;
    const int is64 = *flag;
    int v = is64 ? ei[2 * e] : ei[e];
    if (e < NE) ridx[e] = v; else cidx[e - NE] = v;
}

// ---------------------------------------------------------------------------
// init: h = x @ fc1_w + fc1_b   [NN,32];  coord = coords_init copy
// ---------------------------------------------------------------------------
__global__ __launch_bounds__(256) void init_nodes_kernel(
    const float* __restrict__ x, const float* __restrict__ fc1w,
    const float* __restrict__ fc1b, const float* __restrict__ ci,
    float* __restrict__ h, float* __restrict__ coord)
{
    int idx = blockIdx.x * 256 + threadIdx.x;
    if (idx < NN * 32) {
        int v = idx >> 5, f = idx & 31;
        float acc = fc1b[f];
#pragma unroll
        for (int i = 0; i < 3; i++) acc += x[v * 3 + i] * fc1w[i * 32 + f];
        h[idx] = acc;
    }
    if (idx < NN * 3) coord[idx] = ci[idx];
}

// ---------------------------------------------------------------------------
// CSR-by-col build: counts, scan, scatter
// ---------------------------------------------------------------------------
__global__ __launch_bounds__(256) void count_kernel(
    const int* __restrict__ ridx, const int* __restrict__ cidx,
    int* __restrict__ rowcnt, int* __restrict__ colcnt)
{
    int e = blockIdx.x * 256 + threadIdx.x;
    if (e < NE) { atomicAdd(&rowcnt[ridx[e]], 1); atomicAdd(&colcnt[cidx[e]], 1); }
}

__global__ void scan_kernel(const int* __restrict__ colcnt, const int* __restrict__ rowcnt,
                            int* __restrict__ cstart, int* __restrict__ cnext,
                            float* __restrict__ invc)
{
    __shared__ int part[256];
    const int t = threadIdx.x;
    int sum = 0;
    for (int i = 0; i < 40; i++) { int v = t * 40 + i; if (v < NN) sum += colcnt[v]; }
    part[t] = sum;
    __syncthreads();
    if (t == 0) {
        int run = 0;
        for (int i = 0; i < 256; i++) { int tmp = part[i]; part[i] = run; run += tmp; }
    }
    __syncthreads();
    int run = part[t];
    for (int i = 0; i < 40; i++) {
        int v = t * 40 + i;
        if (v < NN) { cstart[v] = run; cnext[v] = run; run += colcnt[v]; }
    }
    if (t == 255) cstart[NN] = run;
    for (int v = t; v < NN; v += 256) invc[v] = 1.0f / fmaxf((float)rowcnt[v], 1.0f);
}

__global__ __launch_bounds__(256) void scatter_kernel(
    const int* __restrict__ cidx, int* __restrict__ cnext, int* __restrict__ elist)
{
    int e = blockIdx.x * 256 + threadIdx.x;
    if (e < NE) { int pos = atomicAdd(&cnext[cidx[e]], 1); elist[pos] = e; }
}

// ---------------------------------------------------------------------------
// w2 -> fp16 MFMA B-fragment pack: w2h[((c*8+s)*64+l)*8+j] = w2[k][col],
// k = s*16+(l>>5)*8+j, col = c*32+(l&31).  (one-time, 64 KB)
// ---------------------------------------------------------------------------
__global__ __launch_bounds__(256) void w2pack_kernel(
    const float* __restrict__ w2, u16* __restrict__ w2h)
{
    const int slot = blockIdx.x * 256 + threadIdx.x;    // 0..4095
    const int c = slot >> 9, s = (slot >> 6) & 7, l = slot & 63;
    const int li = l & 31, hf = l >> 5;
    const int k0 = s * 16 + hf * 8, col = c * 32 + li;
    u32 pk[8];
#pragma unroll
    for (int j = 0; j < 8; j++) pk[j] = f2h(w2[(size_t)(k0 + j) * 256 + col]);
    uint4 o;
    o.x = pk[0] | (pk[1] << 16);
    o.y = pk[2] | (pk[3] << 16);
    o.z = pk[4] | (pk[5] << 16);
    o.w = pk[6] | (pk[7] << 16);
    *(uint4*)&w2h[(size_t)slot * 8] = o;
}

// ---------------------------------------------------------------------------
// k2 MLP: edge_attr[6] -> 128 -> 256 (relu both). 32 edges/block.
// Layer 1 (VALU) writes k1 straight into fp16 A-fragment order in LDS;
// layer 2 is 8 MFMA steps per col-tile (4 waves x 2 tiles).
// fk2=0: fp16 [e][256].  fk2=1: uint8 [e][256] + per-edge scale k2s[e].
// ---------------------------------------------------------------------------
__global__ __launch_bounds__(256) void mlp_k2_kernel(
    const float* __restrict__ ea,
    const float* __restrict__ w1, const float* __restrict__ b1,
    const u16* __restrict__ w2h, const float* __restrict__ b2,
    u8* __restrict__ k2base, float* __restrict__ k2s, int fk2)
{
    __shared__ __align__(16) float ea_s[32 * 6];
    __shared__ __align__(16) u16   k1f[4096];          // A-frags: [s][lane][j]
    __shared__ __align__(16) float M_s[32 * 260];      // [e][c], padded
    const int t  = threadIdx.x;
    const int e0 = blockIdx.x * 32;

    for (int idx = t; idx < 192; idx += 256)
        ea_s[idx] = ea[(size_t)e0 * 6 + idx];
    __syncthreads();

    // layer 1: [32,6]@[6,128] relu -> fp16 fragments
    for (int slot = t; slot < 512; slot += 256) {
        const int s  = slot >> 6;
        const int l  = slot & 63;
        const int li = l & 31, hf = l >> 5;
        const int k0 = s * 16 + hf * 8;
        float acc[8];
        {
            const float4 ba = *(const float4*)&b1[k0];
            const float4 bb = *(const float4*)&b1[k0 + 4];
            acc[0] = ba.x; acc[1] = ba.y; acc[2] = ba.z; acc[3] = ba.w;
            acc[4] = bb.x; acc[5] = bb.y; acc[6] = bb.z; acc[7] = bb.w;
        }
#pragma unroll
        for (int i = 0; i < 6; i++) {
            const float ev = ea_s[li * 6 + i];
            const float4 wa = *(const float4*)&w1[i * 128 + k0];
            const float4 wb = *(const float4*)&w1[i * 128 + k0 + 4];
            acc[0] += ev * wa.x; acc[1] += ev * wa.y;
            acc[2] += ev * wa.z; acc[3] += ev * wa.w;
            acc[4] += ev * wb.x; acc[5] += ev * wb.y;
            acc[6] += ev * wb.z; acc[7] += ev * wb.w;
        }
        uint4 o;
        o.x = f2h(fmaxf(acc[0], 0.f)) | (f2h(fmaxf(acc[1], 0.f)) << 16);
        o.y = f2h(fmaxf(acc[2], 0.f)) | (f2h(fmaxf(acc[3], 0.f)) << 16);
        o.z = f2h(fmaxf(acc[4], 0.f)) | (f2h(fmaxf(acc[5], 0.f)) << 16);
        o.w = f2h(fmaxf(acc[6], 0.f)) | (f2h(fmaxf(acc[7], 0.f)) << 16);
        *(uint4*)&k1f[slot * 8] = o;
    }
    __syncthreads();

    // layer 2: [32,128]@[128,256] via mfma_32x32x16_f16
    {
        const int w  = t >> 6, l = t & 63;
        const int li = l & 31, hf = l >> 5;
#pragma unroll
        for (int ct = 0; ct < 2; ct++) {
            const int c = w * 2 + ct;
            floatx16 acc;
#pragma unroll
            for (int r = 0; r < 16; r++) acc[r] = 0.f;
#pragma unroll
            for (int s = 0; s < 8; s++) {
                const half8 a = __builtin_bit_cast(half8,
                    *(const uint4*)&k1f[(s * 64 + l) * 8]);
                const half8 b = __builtin_bit_cast(half8,
                    *(const uint4*)&w2h[(((size_t)c * 8 + s) * 64 + l) * 8]);
                acc = __builtin_amdgcn_mfma_f32_32x32x16_f16(a, b, acc, 0, 0, 0);
            }
            const float bb = b2[c * 32 + li];
#pragma unroll
            for (int r = 0; r < 16; r++) {
                const int e = (r & 3) + 8 * (r >> 2) + 4 * hf;
                M_s[e * 260 + c * 32 + li] = fmaxf(acc[r] + bb, 0.f);
            }
        }
    }
    __syncthreads();

    // store k2: thread t -> edge el=t>>3, col-chunk q=t&7 (32 cols each)
    {
        const int el = t >> 3, q = t & 7;
        const size_t eglob = (size_t)e0 + el;
        if (fk2 == 0) {
            u16* outp = (u16*)k2base + eglob * 256 + q * 32;
#pragma unroll
            for (int u = 0; u < 8; u += 2) {
                float4 a = *(float4*)&M_s[el * 260 + q * 32 + u * 4];
                float4 b = *(float4*)&M_s[el * 260 + q * 32 + u * 4 + 4];
                uint4 o;
                o.x = f2h(a.x) | (f2h(a.y) << 16);
                o.y = f2h(a.z) | (f2h(a.w) << 16);
                o.z = f2h(b.x) | (f2h(b.y) << 16);
                o.w = f2h(b.z) | (f2h(b.w) << 16);
                *(uint4*)(outp + u * 4) = o;
            }
        } else {
            // per-edge max over the 8 lanes covering this edge
            float mx = 0.f;
#pragma unroll
            for (int u = 0; u < 32; u++) mx = fmaxf(mx, M_s[el * 260 + q * 32 + u]);
            mx = fmaxf(mx, __shfl_xor(mx, 1, 8));
            mx = fmaxf(mx, __shfl_xor(mx, 2, 8));
            mx = fmaxf(mx, __shfl_xor(mx, 4, 8));
            const float sc  = mx / 255.f;
            const float inv = (mx > 0.f) ? 255.f / mx : 0.f;
            if (q == 0) k2s[eglob] = sc;
            u8* outp = k2base + eglob * 256 + q * 32;
            u32 w[8];
#pragma unroll
            for (int u = 0; u < 8; u++) {
                float4 a = *(float4*)&M_s[el * 260 + q * 32 + u * 4];
                u32 q0 = (u32)fminf(rintf(a.x * inv), 255.f);
                u32 q1 = (u32)fminf(rintf(a.y * inv), 255.f);
                u32 q2 = (u32)fminf(rintf(a.z * inv), 255.f);
                u32 q3 = (u32)fminf(rintf(a.w * inv), 255.f);
                w[u] = q0 | (q1 << 8) | (q2 << 16) | (q3 << 24);
            }
            *(uint4*)outp        = make_uint4(w[0], w[1], w[2], w[3]);
            *(uint4*)(outp + 16) = make_uint4(w[4], w[5], w[6], w[7]);
        }
    }
}

// ---------------------------------------------------------------------------
// Bvec[v][i] = sum_j b3[i*32+j] * h[v][j]
// ---------------------------------------------------------------------------
__global__ __launch_bounds__(256) void bvec_kernel(
    const float* __restrict__ h, const float* __restrict__ b3, float* __restrict__ bvec)
{
    int idx = blockIdx.x * 256 + threadIdx.x;
    if (idx >= NN * 32) return;
    int v = idx >> 5, i = idx & 31;
    const float* hp = &h[(size_t)v * 32];
    const float* bp = &b3[i * 32];
    float acc = 0.f;
#pragma unroll
    for (int c = 0; c < 8; c++) {
        float4 hv = *(const float4*)&hp[c * 4];
        float4 bv = *(const float4*)&bp[c * 4];
        acc += hv.x * bv.x + hv.y * bv.y + hv.z * bv.z + hv.w * bv.w;
    }
    bvec[idx] = acc;
}

// ---------------------------------------------------------------------------
// G in MFMA-B-fragment order, fp16 (u16 offset o = s*512 + lane*8 + j holds
// G[k=s*16+(lane>>5)*8+j][i=lane&31]).  LDS h staging in PACKED FP16 (8 KB;
// halves the r6 version's LDS-pipe load) + v_dot2_f32_f16 (2 MACs/inst,
// fp32 accumulate).  r8's global-load variant was latency-bound (VALU 15%).
// Grid: (ceil(NN/128), 16).
// ---------------------------------------------------------------------------
__global__ __launch_bounds__(256) void g_kernel(
    const float* __restrict__ h, const float* __restrict__ w3,
    u16* __restrict__ Gg)
{
    __shared__ __align__(16) u32 h16[128 * 16];   // fp16 pairs of h, 8 KB
    const int t  = threadIdx.x;
    const int v0 = blockIdx.x * 128;

    // stage h -> packed fp16 LDS (thread: node v=t>>1, half hh=t&1)
    {
        const int v = t >> 1, hh = t & 1;
        float4 a = make_float4(0.f, 0.f, 0.f, 0.f), b = a, c = a, d = a;
        if (v0 + v < NN) {
            const float* hp = &h[(size_t)(v0 + v) * 32 + hh * 16];
            a = *(const float4*)hp;       b = *(const float4*)(hp + 4);
            c = *(const float4*)(hp + 8); d = *(const float4*)(hp + 12);
        }
        uint4 o0, o1;
        o0.x = f2h(a.x) | (f2h(a.y) << 16);
        o0.y = f2h(a.z) | (f2h(a.w) << 16);
        o0.z = f2h(b.x) | (f2h(b.y) << 16);
        o0.w = f2h(b.z) | (f2h(b.w) << 16);
        o1.x = f2h(c.x) | (f2h(c.y) << 16);
        o1.y = f2h(c.z) | (f2h(c.w) << 16);
        o1.z = f2h(d.x) | (f2h(d.y) << 16);
        o1.w = f2h(d.z) | (f2h(d.w) << 16);
        *(uint4*)&h16[v * 16 + hh * 8]     = o0;
        *(uint4*)&h16[v * 16 + hh * 8 + 4] = o1;
    }
    __syncthreads();

    const int by    = blockIdx.y;        // step s, 0..15
    const int lane  = t >> 2;            // 0..63
    const int i     = lane & 31;
    const int halfk = lane >> 5;
    const int j0    = (t & 3) * 2;
    const int k0    = by * 16 + halfk * 8 + j0;

    // two w3 rows as fp16 pairs (32 VGPRs)
    u32 w0p[16], w1p[16];
    {
        const float* wp0 = &w3[(size_t)k0 * 1024 + (size_t)i * 32];
        const float* wp1 = wp0 + 1024;
#pragma unroll
        for (int c = 0; c < 8; c++) {
            const float4 a = *(const float4*)&wp0[c * 4];
            w0p[c * 2]     = f2h(a.x) | (f2h(a.y) << 16);
            w0p[c * 2 + 1] = f2h(a.z) | (f2h(a.w) << 16);
            const float4 b = *(const float4*)&wp1[c * 4];
            w1p[c * 2]     = f2h(b.x) | (f2h(b.y) << 16);
            w1p[c * 2 + 1] = f2h(b.z) | (f2h(b.w) << 16);
        }
    }
    const int vmax = min(128, NN - v0);
    u32* outp = (u32*)Gg;
#pragma unroll 2
    for (int v = 0; v < vmax; v++) {
        float a0 = 0.f, a1 = 0.f;
#pragma unroll
        for (int c = 0; c < 4; c++) {
            const uint4 q = *(const uint4*)&h16[v * 16 + c * 4];
            const half2t h0 = __builtin_bit_cast(half2t, q.x);
            const half2t h1 = __builtin_bit_cast(half2t, q.y);
            const half2t h2 = __builtin_bit_cast(half2t, q.z);
            const half2t h3 = __builtin_bit_cast(half2t, q.w);
            a0 = __builtin_amdgcn_fdot2(h0, __builtin_bit_cast(half2t, w0p[c*4+0]), a0, false);
            a0 = __builtin_amdgcn_fdot2(h1, __builtin_bit_cast(half2t, w0p[c*4+1]), a0, false);
            a0 = __builtin_amdgcn_fdot2(h2, __builtin_bit_cast(half2t, w0p[c*4+2]), a0, false);
            a0 = __builtin_amdgcn_fdot2(h3, __builtin_bit_cast(half2t, w0p[c*4+3]), a0, false);
            a1 = __builtin_amdgcn_fdot2(h0, __builtin_bit_cast(half2t, w1p[c*4+0]), a1, false);
            a1 = __builtin_amdgcn_fdot2(h1, __builtin_bit_cast(half2t, w1p[c*4+1]), a1, false);
            a1 = __builtin_amdgcn_fdot2(h2, __builtin_bit_cast(half2t, w1p[c*4+2]), a1, false);
            a1 = __builtin_amdgcn_fdot2(h3, __builtin_bit_cast(half2t, w1p[c*4+3]), a1, false);
        }
        outp[(size_t)(v0 + v) * 4096 + by * 256 + t] = f2h(a0) | (f2h(a1) << 16);
    }
}

// ---------------------------------------------------------------------------
// MFMA edge pass. One wave64 per col-node n; 4 waves/block (independent).
// C/D layout: col = lane&31, row = (reg&3)+8*(reg>>2)+4*(lane>>5).
// ---------------------------------------------------------------------------
__global__ __launch_bounds__(256) void edge_kernel(
    const int* __restrict__ cstart, const int* __restrict__ elist,
    const int* __restrict__ ridx, const u8* __restrict__ k2base,
    const float* __restrict__ k2s, const u16* __restrict__ Gg,
    const float* __restrict__ coord,
    const float* __restrict__ cm1w, const float* __restrict__ cm1b,
    const float* __restrict__ cm2w, const float* __restrict__ cm2b,
    const float* __restrict__ bvec, float* __restrict__ agg,
    float* __restrict__ dco, int fk2)
{
    const int t    = threadIdx.x;
    const int w    = t >> 6;         // wave in block
    const int l    = t & 63;         // lane
    const int li   = l & 31;         // column index / lane-in-half
    const int half = l >> 5;

    __shared__ __align__(16) float Mlds_all[4][32 * 36];
    float* Mlds = Mlds_all[w];

    // cm1 B-fragments + cm2 (node-independent)
    half8 cmb[2];
#pragma unroll
    for (int s2 = 0; s2 < 2; s2++)
#pragma unroll
        for (int j = 0; j < 8; j++)
            cmb[s2][j] = (_Float16)cm1w[(s2 * 16 + half * 8 + j) * 32 + li];
    const float cm1bq = cm1b[li];
    const float cm2q  = cm2w[li];
    const float cm2b0 = cm2b[0];

    const int n = blockIdx.x * 4 + w;
    if (n >= NN) return;
    const int s0  = cstart[n];
    const int deg = cstart[n + 1] - s0;
    if (deg == 0) return;

    const float bv  = bvec[n * 32 + li];
    const float con = (li < 3) ? coord[(size_t)n * 3 + li] : 0.f;
    const u16* Gn = Gg + (size_t)n * 8192;

    for (int base = 0; base < deg; base += 32) {
        const int mye   = base + li;
        const int valid = (mye < deg) ? 1 : 0;
        const int eid   = valid ? elist[s0 + mye] : 0;
        const int rowv  = valid ? ridx[eid] : 0;

        floatx16 acc;
#pragma unroll
        for (int r = 0; r < 16; r++) acc[r] = bv;

        if (fk2 == 1) {
            const float se = valid ? k2s[eid] : 0.f;
            const u8* k2row = k2base + (size_t)eid * 256 + half * 8;
#pragma unroll
            for (int s = 0; s < 16; s++) {
                const uint2 wd = *(const uint2*)(k2row + s * 16);
                half8 a;
#pragma unroll
                for (int j = 0; j < 4; j++) {
                    a[j]     = (_Float16)((float)((wd.x >> (8 * j)) & 0xffu) * se);
                    a[4 + j] = (_Float16)((float)((wd.y >> (8 * j)) & 0xffu) * se);
                }
                const half8 b = __builtin_bit_cast(half8,
                    *(const uint4*)(Gn + s * 512 + l * 8));
                acc = __builtin_amdgcn_mfma_f32_32x32x16_f16(a, b, acc, 0, 0, 0);
            }
        } else {
            const u16* k2row = (const u16*)k2base + (size_t)eid * 256 + half * 8;
#pragma unroll
            for (int s = 0; s < 16; s++) {
                const half8 a = __builtin_bit_cast(half8, *(const uint4*)(k2row + s * 16));
                const half8 b = __builtin_bit_cast(half8,
                    *(const uint4*)(Gn + s * 512 + l * 8));
                acc = __builtin_amdgcn_mfma_f32_32x32x16_f16(a, b, acc, 0, 0, 0);
            }
        }

        // M -> LDS (fp32, stride 36 for bank spread / 16B alignment)
#pragma unroll
        for (int r = 0; r < 16; r++) {
            const int e = (r & 3) + 8 * (r >> 2) + 4 * half;
            Mlds[e * 36 + li] = acc[r];
        }
        asm volatile("s_waitcnt lgkmcnt(0)" ::: "memory");

        // T = cm1b + M @ cm1
        floatx16 acc2;
#pragma unroll
        for (int r = 0; r < 16; r++) acc2[r] = cm1bq;
#pragma unroll
        for (int s2 = 0; s2 < 2; s2++) {
            const float* mp = &Mlds[li * 36 + s2 * 16 + half * 8];
            const float4 m0 = *(const float4*)mp;
            const float4 m1 = *(const float4*)(mp + 4);
            half8 a;
            a[0] = (_Float16)m0.x; a[1] = (_Float16)m0.y;
            a[2] = (_Float16)m0.z; a[3] = (_Float16)m0.w;
            a[4] = (_Float16)m1.x; a[5] = (_Float16)m1.y;
            a[6] = (_Float16)m1.z; a[7] = (_Float16)m1.w;
            acc2 = __builtin_amdgcn_mfma_f32_32x32x16_f16(a, cmb[s2], acc2, 0, 0, 0);
        }

        // epilogue: per C-reg r -> edge e; we-reduction + atomics
#pragma unroll
        for (int r = 0; r < 16; r++) {
            const int e  = (r & 3) + 8 * (r >> 2) + 4 * half;
            const int vr = __shfl(valid, e, 32);
            const int rr = __shfl(rowv, e, 32);
            float part = fmaxf(acc2[r], 0.f) * cm2q;
            part += __shfl_xor(part, 1, 32);
            part += __shfl_xor(part, 2, 32);
            part += __shfl_xor(part, 4, 32);
            part += __shfl_xor(part, 8, 32);
            part += __shfl_xor(part, 16, 32);
            const float wer = part + cm2b0;
            if (vr) {
                atomicAdd(&agg[(size_t)rr * 32 + li], acc[r]);
                if (li < 3) {
                    const float d = coord[(size_t)rr * 3 + li] - con;
                    atomicAdd(&dco[(size_t)rr * 3 + li], d * wer);
                }
            }
        }
    }
}

// ---------------------------------------------------------------------------
__global__ __launch_bounds__(256) void node_update_kernel(
    float* __restrict__ h, float* __restrict__ agg,
    float* __restrict__ coord, float* __restrict__ dco,
    const float* __restrict__ invc)
{
    int idx = blockIdx.x * 256 + threadIdx.x;
    if (idx < NN * 32) {
        int v = idx >> 5;
        h[idx] = fmaxf(h[idx] + agg[idx] * invc[v], 0.f);
        agg[idx] = 0.f;
    }
    if (idx < NN * 3) {
        coord[idx] += dco[idx] * invc[idx / 3];
        dco[idx] = 0.f;
    }
}

// ---------------------------------------------------------------------------
__global__ __launch_bounds__(256) void final_kernel(
    const float* __restrict__ h, const float* __restrict__ coord,
    const float* __restrict__ wa, const float* __restrict__ ba,
    const float* __restrict__ wb, const float* __restrict__ bb,
    float* __restrict__ out)
{
    const int lane = threadIdx.x & 63;
    const int v = blockIdx.x * 4 + (threadIdx.x >> 6);
    if (v >= NN) return;
    const float hreg = (lane < 32) ? h[(size_t)v * 32 + lane] : 0.f;
    float acc = ba[lane];
#pragma unroll
    for (int f = 0; f < 32; f++) acc += __shfl(hreg, f, 64) * wa[f * 64 + lane];
    float part = fmaxf(acc, 0.f) * wb[lane];
#pragma unroll
    for (int off = 32; off >= 1; off >>= 1) part += __shfl_xor(part, off, 64);
    if (lane == 0) out[v] = part + bb[0];
    if (lane < 3) out[NN + (size_t)v * 3 + lane] = coord[(size_t)v * 3 + lane];
}

// ---------------------------------------------------------------------------
extern "C" void kernel_launch(void* const* d_in, const int* in_sizes, int n_in,
                              void* d_out, int out_size, void* d_ws, size_t ws_size,
                              hipStream_t stream)
{
    const float* x    = (const float*)d_in[0];
    const int*   ei   = (const int*)d_in[1];
    const float* ea   = (const float*)d_in[2];
    const float* ci   = (const float*)d_in[3];
    const float* fc1w = (const float*)d_in[4];
    const float* fc1b = (const float*)d_in[5];
    const float* k1w  = (const float*)d_in[6];
    const float* k1b  = (const float*)d_in[7];
    const float* k2w  = (const float*)d_in[8];
    const float* k2b  = (const float*)d_in[9];
    const float* k3w  = (const float*)d_in[10];
    const float* k3b  = (const float*)d_in[11];
    const float* cm1w = (const float*)d_in[12];
    const float* cm1b = (const float*)d_in[13];
    const float* cm2w = (const float*)d_in[14];
    const float* cm2b = (const float*)d_in[15];
    const float* f2aw = (const float*)d_in[16];
    const float* f2ab = (const float*)d_in[17];
    const float* f2bw = (const float*)d_in[18];
    const float* f2bb = (const float*)d_in[19];

    // ---- workspace carve; tiers: A=(2) fp16 k2, B=(1) u8 k2. G always fp16.
    size_t o_k2, o_k2s, o_G, o_h, o_agg, o_bv, o_coord, o_dco, o_invc, o_rc,
           o_cc, o_cs, o_cn, o_el, o_ri, o_ci, o_w2h;
#define ALGN(v) (((v) + 255) & ~(size_t)255)
    auto carve = [&](size_t k2es) -> size_t {
        size_t o = 0;
        o_k2   = o; o += ALGN((size_t)NE * 256 * k2es);
        o_k2s  = o; o += ALGN((size_t)NE * 4);
        o_G    = o; o += ALGN((size_t)NN * 8192 * 2);
        o_h    = o; o += ALGN((size_t)NN * 32 * 4);
        o_agg  = o; o += ALGN((size_t)NN * 32 * 4);
        o_bv   = o; o += ALGN((size_t)NN * 32 * 4);
        o_coord= o; o += ALGN((size_t)NN * 3 * 4);
        o_dco  = o; o += ALGN((size_t)NN * 3 * 4);
        o_invc = o; o += ALGN((size_t)NN * 4);
        o_rc   = o; o += ALGN((size_t)NN * 4);
        o_cc   = o; o += ALGN((size_t)NN * 4);
        o_cs   = o; o += ALGN((size_t)(NN + 1) * 4);
        o_cn   = o; o += ALGN((size_t)NN * 4);
        o_el   = o; o += ALGN((size_t)NE * 4);
        o_ri   = o; o += ALGN((size_t)NE * 4);
        o_ci   = o; o += ALGN((size_t)NE * 4);
        o_w2h  = o; o += ALGN((size_t)128 * 256 * 2);
        return o;
    };
    int fk2;
    if      (ws_size >= carve(2)) { fk2 = 0; carve(2); }  // ~328 MB
    else if (ws_size >= carve(1)) { fk2 = 1; carve(1); }  // ~251 MB
    else {
        sentinel_kernel<<<(NN * 4 + 255) / 256, 256, 0, stream>>>((float*)d_out, NN * 4, 1.0e6f);
        return;
    }

    char* wsb = (char*)d_ws;
    u8*    k2g   = (u8*)(wsb + o_k2);
    float* k2s   = (float*)(wsb + o_k2s);
    u16*   Gg    = (u16*)(wsb + o_G);
    float* h     = (float*)(wsb + o_h);
    float* agg   = (float*)(wsb + o_agg);
    float* bvec  = (float*)(wsb + o_bv);
    float* coord = (float*)(wsb + o_coord);
    float* dco   = (float*)(wsb + o_dco);
    float* invc  = (float*)(wsb + o_invc);
    int*   rowcnt= (int*)(wsb + o_rc);
    int*   colcnt= (int*)(wsb + o_cc);
    int*   cstart= (int*)(wsb + o_cs);
    int*   cnext = (int*)(wsb + o_cn);
    int*   elist = (int*)(wsb + o_el);
    int*   ridx  = (int*)(wsb + o_ri);
    int*   cidx  = (int*)(wsb + o_ci);
    u16*   w2h   = (u16*)(wsb + o_w2h);

    hipMemsetAsync(agg,    0, (size_t)NN * 32 * 4, stream);
    hipMemsetAsync(dco,    0, (size_t)NN * 3 * 4, stream);
    hipMemsetAsync(rowcnt, 0, (size_t)NN * 4, stream);
    hipMemsetAsync(colcnt, 0, (size_t)NN * 4, stream);

    detect_idx_kernel<<<1, 256, 0, stream>>>(ei, cnext);   // cnext[0] as flag temp
    convert_idx_kernel<<<(2 * NE + 255) / 256, 256, 0, stream>>>(ei, cnext, ridx, cidx);
    init_nodes_kernel<<<(NN * 32 + 255) / 256, 256, 0, stream>>>(x, fc1w, fc1b, ci, h, coord);
    count_kernel<<<(NE + 255) / 256, 256, 0, stream>>>(ridx, cidx, rowcnt, colcnt);
    scan_kernel<<<1, 256, 0, stream>>>(colcnt, rowcnt, cstart, cnext, invc);
    scatter_kernel<<<(NE + 255) / 256, 256, 0, stream>>>(cidx, cnext, elist);
    w2pack_kernel<<<16, 256, 0, stream>>>(k2w, w2h);
    mlp_k2_kernel<<<NE / 32, 256, 0, stream>>>(ea, k1w, k1b, w2h, k2b, k2g, k2s, fk2);

    const dim3 ggrid((NN + 127) / 128, 16);
    for (int l = 0; l < DEPTH; l++) {
        bvec_kernel<<<(NN * 32 + 255) / 256, 256, 0, stream>>>(h, k3b, bvec);
        g_kernel<<<ggrid, 256, 0, stream>>>(h, k3w, Gg);
        edge_kernel<<<(NN + 3) / 4, 256, 0, stream>>>(cstart, elist, ridx, k2g, k2s,
                                                      Gg, coord, cm1w, cm1b, cm2w, cm2b,
                                                      bvec, agg, dco, fk2);
        node_update_kernel<<<(NN * 32 + 255) / 256, 256, 0, stream>>>(h, agg, coord, dco, invc);
    }
    final_kernel<<<(NN + 3) / 4, 256, 0, stream>>>(h, coord, f2aw, f2ab, f2bw, f2bb,
                                                   (float*)d_out);
}

// Round 10
// 963.928 us; speedup vs baseline: 2.1714x; 1.1088x over previous
//
#include <hip/hip_runtime.h>

// EGKN: E(n) graph kernel network.
#define NN 10000      // nodes
#define NE 300000     // edges
#define DEPTH 4

typedef unsigned int   u32;
typedef unsigned short u16;
typedef unsigned char  u8;

typedef _Float16 half8  __attribute__((ext_vector_type(8)));
typedef _Float16 half2t __attribute__((ext_vector_type(2)));
typedef float  floatx16 __attribute__((ext_vector_type(16)));

// fp16 encode/decode via hardware v_cvt (with saturation on encode)
__device__ __forceinline__ u32 f2h(float f) {
    f = fminf(fmaxf(f, -60000.f), 60000.f);
    _Float16 h = (_Float16)f;
    return (u32)__builtin_bit_cast(u16, h);
}
__device__ __forceinline__ float h2f(u16 b) {
    return (float)__builtin_bit_cast(_Float16, b);
}

// ---------------------------------------------------------------------------
__global__ void sentinel_kernel(float* out, int n, float val) {
    int i = blockIdx.x * 256 + threadIdx.x;
    if (i < n) out[i] = val;
}

// ---------------------------------------------------------------------------
// edge_index dtype normalization (int64 vs int32)
// ---------------------------------------------------------------------------
__global__ void detect_idx_kernel(const int* __restrict__ ei, int* __restrict__ flag) {
    __shared__ int nz;
    if (threadIdx.x == 0) nz = 0;
    __syncthreads();
    if (ei[threadIdx.x * 2 + 1] != 0) atomicAdd(&nz, 1);
    __syncthreads();
    if (threadIdx.x == 0) *flag = (nz == 0) ? 1 : 0;   // 1 => int64
}

__global__ __launch_bounds__(256) void convert_idx_kernel(
    const int* __restrict__ ei, const int* __restrict__ flag,
    int* __restrict__ ridx, int* __restrict__ cidx)
{
    int e = blockIdx.x * 256 + threadIdx.x;
    if (e >= 2 * NE) return;
    const int is64 = *flag;
    int v = is64 ? ei[2 * e] : ei[e];
    if (e < NE) ridx[e] = v; else cidx[e - NE] = v;
}

// ---------------------------------------------------------------------------
// init: h = x @ fc1_w + fc1_b   [NN,32];  coord = coords_init copy
// ---------------------------------------------------------------------------
__global__ __launch_bounds__(256) void init_nodes_kernel(
    const float* __restrict__ x, const float* __restrict__ fc1w,
    const float* __restrict__ fc1b, const float* __restrict__ ci,
    float* __restrict__ h, float* __restrict__ coord)
{
    int idx = blockIdx.x * 256 + threadIdx.x;
    if (idx < NN * 32) {
        int v = idx >> 5, f = idx & 31;
        float acc = fc1b[f];
#pragma unroll
        for (int i = 0; i < 3; i++) acc += x[v * 3 + i] * fc1w[i * 32 + f];
        h[idx] = acc;
    }
    if (idx < NN * 3) coord[idx] = ci[idx];
}

// ---------------------------------------------------------------------------
// CSR-by-col build: counts, scan, scatter
// ---------------------------------------------------------------------------
__global__ __launch_bounds__(256) void count_kernel(
    const int* __restrict__ ridx, const int* __restrict__ cidx,
    int* __restrict__ rowcnt, int* __restrict__ colcnt)
{
    int e = blockIdx.x * 256 + threadIdx.x;
    if (e < NE) { atomicAdd(&rowcnt[ridx[e]], 1); atomicAdd(&colcnt[cidx[e]], 1); }
}

__global__ void scan_kernel(const int* __restrict__ colcnt, const int* __restrict__ rowcnt,
                            int* __restrict__ cstart, int* __restrict__ cnext,
                            float* __restrict__ invc)
{
    __shared__ int part[256];
    const int t = threadIdx.x;
    int sum = 0;
    for (int i = 0; i < 40; i++) { int v = t * 40 + i; if (v < NN) sum += colcnt[v]; }
    part[t] = sum;
    __syncthreads();
    if (t == 0) {
        int run = 0;
        for (int i = 0; i < 256; i++) { int tmp = part[i]; part[i] = run; run += tmp; }
    }
    __syncthreads();
    int run = part[t];
    for (int i = 0; i < 40; i++) {
        int v = t * 40 + i;
        if (v < NN) { cstart[v] = run; cnext[v] = run; run += colcnt[v]; }
    }
    if (t == 255) cstart[NN] = run;
    for (int v = t; v < NN; v += 256) invc[v] = 1.0f / fmaxf((float)rowcnt[v], 1.0f);
}

__global__ __launch_bounds__(256) void scatter_kernel(
    const int* __restrict__ cidx, int* __restrict__ cnext, int* __restrict__ elist)
{
    int e = blockIdx.x * 256 + threadIdx.x;
    if (e < NE) { int pos = atomicAdd(&cnext[cidx[e]], 1); elist[pos] = e; }
}

// ---------------------------------------------------------------------------
// w2 -> fp16 MFMA B-fragment pack: w2h[((c*8+s)*64+l)*8+j] = w2[k][col],
// k = s*16+(l>>5)*8+j, col = c*32+(l&31).  (one-time, 64 KB)
// ---------------------------------------------------------------------------
__global__ __launch_bounds__(256) void w2pack_kernel(
    const float* __restrict__ w2, u16* __restrict__ w2h)
{
    const int slot = blockIdx.x * 256 + threadIdx.x;    // 0..4095
    const int c = slot >> 9, s = (slot >> 6) & 7, l = slot & 63;
    const int li = l & 31, hf = l >> 5;
    const int k0 = s * 16 + hf * 8, col = c * 32 + li;
    u32 pk[8];
#pragma unroll
    for (int j = 0; j < 8; j++) pk[j] = f2h(w2[(size_t)(k0 + j) * 256 + col]);
    uint4 o;
    o.x = pk[0] | (pk[1] << 16);
    o.y = pk[2] | (pk[3] << 16);
    o.z = pk[4] | (pk[5] << 16);
    o.w = pk[6] | (pk[7] << 16);
    *(uint4*)&w2h[(size_t)slot * 8] = o;
}

// ---------------------------------------------------------------------------
// k2 MLP: edge_attr[6] -> 128 -> 256 (relu both). 32 edges/block.
// Layer 1 (VALU) writes k1 straight into fp16 A-fragment order in LDS;
// layer 2 is 8 MFMA steps per col-tile (4 waves x 2 tiles).
// fk2=0: fp16 [e][256].  fk2=1: uint8 [e][256] + per-edge scale k2s[e].
// ---------------------------------------------------------------------------
__global__ __launch_bounds__(256) void mlp_k2_kernel(
    const float* __restrict__ ea,
    const float* __restrict__ w1, const float* __restrict__ b1,
    const u16* __restrict__ w2h, const float* __restrict__ b2,
    u8* __restrict__ k2base, float* __restrict__ k2s, int fk2)
{
    __shared__ __align__(16) float ea_s[32 * 6];
    __shared__ __align__(16) u16   k1f[4096];          // A-frags: [s][lane][j]
    __shared__ __align__(16) float M_s[32 * 260];      // [e][c], padded
    const int t  = threadIdx.x;
    const int e0 = blockIdx.x * 32;

    for (int idx = t; idx < 192; idx += 256)
        ea_s[idx] = ea[(size_t)e0 * 6 + idx];
    __syncthreads();

    // layer 1: [32,6]@[6,128] relu -> fp16 fragments
    for (int slot = t; slot < 512; slot += 256) {
        const int s  = slot >> 6;
        const int l  = slot & 63;
        const int li = l & 31, hf = l >> 5;
        const int k0 = s * 16 + hf * 8;
        float acc[8];
        {
            const float4 ba = *(const float4*)&b1[k0];
            const float4 bb = *(const float4*)&b1[k0 + 4];
            acc[0] = ba.x; acc[1] = ba.y; acc[2] = ba.z; acc[3] = ba.w;
            acc[4] = bb.x; acc[5] = bb.y; acc[6] = bb.z; acc[7] = bb.w;
        }
#pragma unroll
        for (int i = 0; i < 6; i++) {
            const float ev = ea_s[li * 6 + i];
            const float4 wa = *(const float4*)&w1[i * 128 + k0];
            const float4 wb = *(const float4*)&w1[i * 128 + k0 + 4];
            acc[0] += ev * wa.x; acc[1] += ev * wa.y;
            acc[2] += ev * wa.z; acc[3] += ev * wa.w;
            acc[4] += ev * wb.x; acc[5] += ev * wb.y;
            acc[6] += ev * wb.z; acc[7] += ev * wb.w;
        }
        uint4 o;
        o.x = f2h(fmaxf(acc[0], 0.f)) | (f2h(fmaxf(acc[1], 0.f)) << 16);
        o.y = f2h(fmaxf(acc[2], 0.f)) | (f2h(fmaxf(acc[3], 0.f)) << 16);
        o.z = f2h(fmaxf(acc[4], 0.f)) | (f2h(fmaxf(acc[5], 0.f)) << 16);
        o.w = f2h(fmaxf(acc[6], 0.f)) | (f2h(fmaxf(acc[7], 0.f)) << 16);
        *(uint4*)&k1f[slot * 8] = o;
    }
    __syncthreads();

    // layer 2: [32,128]@[128,256] via mfma_32x32x16_f16
    {
        const int w  = t >> 6, l = t & 63;
        const int li = l & 31, hf = l >> 5;
#pragma unroll
        for (int ct = 0; ct < 2; ct++) {
            const int c = w * 2 + ct;
            floatx16 acc;
#pragma unroll
            for (int r = 0; r < 16; r++) acc[r] = 0.f;
#pragma unroll
            for (int s = 0; s < 8; s++) {
                const half8 a = __builtin_bit_cast(half8,
                    *(const uint4*)&k1f[(s * 64 + l) * 8]);
                const half8 b = __builtin_bit_cast(half8,
                    *(const uint4*)&w2h[(((size_t)c * 8 + s) * 64 + l) * 8]);
                acc = __builtin_amdgcn_mfma_f32_32x32x16_f16(a, b, acc, 0, 0, 0);
            }
            const float bb = b2[c * 32 + li];
#pragma unroll
            for (int r = 0; r < 16; r++) {
                const int e = (r & 3) + 8 * (r >> 2) + 4 * hf;
                M_s[e * 260 + c * 32 + li] = fmaxf(acc[r] + bb, 0.f);
            }
        }
    }
    __syncthreads();

    // store k2: thread t -> edge el=t>>3, col-chunk q=t&7 (32 cols each)
    {
        const int el = t >> 3, q = t & 7;
        const size_t eglob = (size_t)e0 + el;
        if (fk2 == 0) {
            u16* outp = (u16*)k2base + eglob * 256 + q * 32;
#pragma unroll
            for (int u = 0; u < 8; u += 2) {
                float4 a = *(float4*)&M_s[el * 260 + q * 32 + u * 4];
                float4 b = *(float4*)&M_s[el * 260 + q * 32 + u * 4 + 4];
                uint4 o;
                o.x = f2h(a.x) | (f2h(a.y) << 16);
                o.y = f2h(a.z) | (f2h(a.w) << 16);
                o.z = f2h(b.x) | (f2h(b.y) << 16);
                o.w = f2h(b.z) | (f2h(b.w) << 16);
                *(uint4*)(outp + u * 4) = o;
            }
        } else {
            // per-edge max over the 8 lanes covering this edge
            float mx = 0.f;
#pragma unroll
            for (int u = 0; u < 32; u++) mx = fmaxf(mx, M_s[el * 260 + q * 32 + u]);
            mx = fmaxf(mx, __shfl_xor(mx, 1, 8));
            mx = fmaxf(mx, __shfl_xor(mx, 2, 8));
            mx = fmaxf(mx, __shfl_xor(mx, 4, 8));
            const float sc  = mx / 255.f;
            const float inv = (mx > 0.f) ? 255.f / mx : 0.f;
            if (q == 0) k2s[eglob] = sc;
            u8* outp = k2base + eglob * 256 + q * 32;
            u32 w[8];
#pragma unroll
            for (int u = 0; u < 8; u++) {
                float4 a = *(float4*)&M_s[el * 260 + q * 32 + u * 4];
                u32 q0 = (u32)fminf(rintf(a.x * inv), 255.f);
                u32 q1 = (u32)fminf(rintf(a.y * inv), 255.f);
                u32 q2 = (u32)fminf(rintf(a.z * inv), 255.f);
                u32 q3 = (u32)fminf(rintf(a.w * inv), 255.f);
                w[u] = q0 | (q1 << 8) | (q2 << 16) | (q3 << 24);
            }
            *(uint4*)outp        = make_uint4(w[0], w[1], w[2], w[3]);
            *(uint4*)(outp + 16) = make_uint4(w[4], w[5], w[6], w[7]);
        }
    }
}

// ---------------------------------------------------------------------------
// Bvec[v][i] = sum_j b3[i*32+j] * h[v][j]
// ---------------------------------------------------------------------------
__global__ __launch_bounds__(256) void bvec_kernel(
    const float* __restrict__ h, const float* __restrict__ b3, float* __restrict__ bvec)
{
    int idx = blockIdx.x * 256 + threadIdx.x;
    if (idx >= NN * 32) return;
    int v = idx >> 5, i = idx & 31;
    const float* hp = &h[(size_t)v * 32];
    const float* bp = &b3[i * 32];
    float acc = 0.f;
#pragma unroll
    for (int c = 0; c < 8; c++) {
        float4 hv = *(const float4*)&hp[c * 4];
        float4 bv = *(const float4*)&bp[c * 4];
        acc += hv.x * bv.x + hv.y * bv.y + hv.z * bv.z + hv.w * bv.w;
    }
    bvec[idx] = acc;
}

// ---------------------------------------------------------------------------
// G in MFMA-B-fragment order, fp16. LDS h staging in packed fp16 + fdot2.
// Grid: (ceil(NN/128), 16).
// ---------------------------------------------------------------------------
__global__ __launch_bounds__(256) void g_kernel(
    const float* __restrict__ h, const float* __restrict__ w3,
    u16* __restrict__ Gg)
{
    __shared__ __align__(16) u32 h16[128 * 16];   // fp16 pairs of h, 8 KB
    const int t  = threadIdx.x;
    const int v0 = blockIdx.x * 128;

    // stage h -> packed fp16 LDS (thread: node v=t>>1, half hh=t&1)
    {
        const int v = t >> 1, hh = t & 1;
        float4 a = make_float4(0.f, 0.f, 0.f, 0.f), b = a, c = a, d = a;
        if (v0 + v < NN) {
            const float* hp = &h[(size_t)(v0 + v) * 32 + hh * 16];
            a = *(const float4*)hp;       b = *(const float4*)(hp + 4);
            c = *(const float4*)(hp + 8); d = *(const float4*)(hp + 12);
        }
        uint4 o0, o1;
        o0.x = f2h(a.x) | (f2h(a.y) << 16);
        o0.y = f2h(a.z) | (f2h(a.w) << 16);
        o0.z = f2h(b.x) | (f2h(b.y) << 16);
        o0.w = f2h(b.z) | (f2h(b.w) << 16);
        o1.x = f2h(c.x) | (f2h(c.y) << 16);
        o1.y = f2h(c.z) | (f2h(c.w) << 16);
        o1.z = f2h(d.x) | (f2h(d.y) << 16);
        o1.w = f2h(d.z) | (f2h(d.w) << 16);
        *(uint4*)&h16[v * 16 + hh * 8]     = o0;
        *(uint4*)&h16[v * 16 + hh * 8 + 4] = o1;
    }
    __syncthreads();

    const int by    = blockIdx.y;        // step s, 0..15
    const int lane  = t >> 2;            // 0..63
    const int i     = lane & 31;
    const int halfk = lane >> 5;
    const int j0    = (t & 3) * 2;
    const int k0    = by * 16 + halfk * 8 + j0;

    // two w3 rows as fp16 pairs (32 VGPRs)
    u32 w0p[16], w1p[16];
    {
        const float* wp0 = &w3[(size_t)k0 * 1024 + (size_t)i * 32];
        const float* wp1 = wp0 + 1024;
#pragma unroll
        for (int c = 0; c < 8; c++) {
            const float4 a = *(const float4*)&wp0[c * 4];
            w0p[c * 2]     = f2h(a.x) | (f2h(a.y) << 16);
            w0p[c * 2 + 1] = f2h(a.z) | (f2h(a.w) << 16);
            const float4 b = *(const float4*)&wp1[c * 4];
            w1p[c * 2]     = f2h(b.x) | (f2h(b.y) << 16);
            w1p[c * 2 + 1] = f2h(b.z) | (f2h(b.w) << 16);
        }
    }
    const int vmax = min(128, NN - v0);
    u32* outp = (u32*)Gg;
#pragma unroll 2
    for (int v = 0; v < vmax; v++) {
        float a0 = 0.f, a1 = 0.f;
#pragma unroll
        for (int c = 0; c < 4; c++) {
            const uint4 q = *(const uint4*)&h16[v * 16 + c * 4];
            const half2t h0 = __builtin_bit_cast(half2t, q.x);
            const half2t h1 = __builtin_bit_cast(half2t, q.y);
            const half2t h2 = __builtin_bit_cast(half2t, q.z);
            const half2t h3 = __builtin_bit_cast(half2t, q.w);
            a0 = __builtin_amdgcn_fdot2(h0, __builtin_bit_cast(half2t, w0p[c*4+0]), a0, false);
            a0 = __builtin_amdgcn_fdot2(h1, __builtin_bit_cast(half2t, w0p[c*4+1]), a0, false);
            a0 = __builtin_amdgcn_fdot2(h2, __builtin_bit_cast(half2t, w0p[c*4+2]), a0, false);
            a0 = __builtin_amdgcn_fdot2(h3, __builtin_bit_cast(half2t, w0p[c*4+3]), a0, false);
            a1 = __builtin_amdgcn_fdot2(h0, __builtin_bit_cast(half2t, w1p[c*4+0]), a1, false);
            a1 = __builtin_amdgcn_fdot2(h1, __builtin_bit_cast(half2t, w1p[c*4+1]), a1, false);
            a1 = __builtin_amdgcn_fdot2(h2, __builtin_bit_cast(half2t, w1p[c*4+2]), a1, false);
            a1 = __builtin_amdgcn_fdot2(h3, __builtin_bit_cast(half2t, w1p[c*4+3]), a1, false);
        }
        outp[(size_t)(v0 + v) * 4096 + by * 256 + t] = f2h(a0) | (f2h(a1) << 16);
    }
}

// ---------------------------------------------------------------------------
// MFMA edge pass. One wave64 per col-node n; 4 waves/block (independent).
// Per tile: PRELOAD all k2+G fragments (breaks r9's 16 serialized HBM round
// trips), 16-MFMA M chain, agg atomics, then coord-MLP where the we-row-sum
// is a 3rd MFMA against an all-ones B (replaces 112 DS-pipe shuffles).
// C/D layout: col = lane&31, row = (reg&3)+8*(reg>>2)+4*(lane>>5).
// ---------------------------------------------------------------------------
__global__ __launch_bounds__(256) void edge_kernel(
    const int* __restrict__ cstart, const int* __restrict__ elist,
    const int* __restrict__ ridx, const u8* __restrict__ k2base,
    const float* __restrict__ k2s, const u16* __restrict__ Gg,
    const float* __restrict__ coord,
    const float* __restrict__ cm1w, const float* __restrict__ cm1b,
    const float* __restrict__ cm2w, const float* __restrict__ cm2b,
    const float* __restrict__ bvec, float* __restrict__ agg,
    float* __restrict__ dco, int fk2)
{
    const int t    = threadIdx.x;
    const int w    = t >> 6;         // wave in block
    const int l    = t & 63;         // lane
    const int li   = l & 31;         // column index / lane-in-half
    const int half = l >> 5;

    __shared__ __align__(16) float Mlds_all[4][32 * 36];
    __shared__ int rowS_all[4][32];
    float* Mlds = Mlds_all[w];
    int*   rowS = rowS_all[w];

    const int n = blockIdx.x * 4 + w;
    if (n >= NN) return;
    const int s0  = cstart[n];
    const int deg = cstart[n + 1] - s0;
    if (deg == 0) return;

    // cm1 B-fragments, ones-B, cm2 (node-independent)
    half8 cmb[2];
#pragma unroll
    for (int s2 = 0; s2 < 2; s2++)
#pragma unroll
        for (int j = 0; j < 8; j++)
            cmb[s2][j] = (_Float16)cm1w[(s2 * 16 + half * 8 + j) * 32 + li];
    half8 onesb;
#pragma unroll
    for (int j = 0; j < 8; j++) onesb[j] = (_Float16)1.0f;
    const float cm1bq = cm1b[li];
    const float cm2q  = cm2w[li];
    const float cm2b0 = cm2b[0];

    const float bv  = bvec[n * 32 + li];
    const float con = (li < 3) ? coord[(size_t)n * 3 + li] : 0.f;
    const u16* Gn = Gg + (size_t)n * 8192;

    for (int base = 0; base < deg; base += 32) {
        const int mye   = base + li;
        const int valid = (mye < deg) ? 1 : 0;
        const int eid   = valid ? elist[s0 + mye] : 0;
        const int rowv  = valid ? ridx[eid] : 0;
        if (l < 32) rowS[l] = rowv;

        // ---- preload ALL fragments (32 vmem ops in flight) ----
        uint4 gr[16];
#pragma unroll
        for (int s = 0; s < 16; s++)
            gr[s] = *(const uint4*)(Gn + s * 512 + l * 8);

        floatx16 acc;
#pragma unroll
        for (int r = 0; r < 16; r++) acc[r] = bv;

        if (fk2 == 1) {
            const float se = valid ? k2s[eid] : 0.f;
            const u8* k2row = k2base + (size_t)eid * 256 + half * 8;
            uint2 kr[16];
#pragma unroll
            for (int s = 0; s < 16; s++) kr[s] = *(const uint2*)(k2row + s * 16);
#pragma unroll
            for (int s = 0; s < 16; s++) {
                half8 a;
#pragma unroll
                for (int j = 0; j < 4; j++) {
                    a[j]     = (_Float16)((float)((kr[s].x >> (8 * j)) & 0xffu) * se);
                    a[4 + j] = (_Float16)((float)((kr[s].y >> (8 * j)) & 0xffu) * se);
                }
                acc = __builtin_amdgcn_mfma_f32_32x32x16_f16(
                    a, __builtin_bit_cast(half8, gr[s]), acc, 0, 0, 0);
            }
        } else {
            const u16* k2row = (const u16*)k2base + (size_t)eid * 256 + half * 8;
            uint4 kr[16];
#pragma unroll
            for (int s = 0; s < 16; s++) kr[s] = *(const uint4*)(k2row + s * 16);
#pragma unroll
            for (int s = 0; s < 16; s++)
                acc = __builtin_amdgcn_mfma_f32_32x32x16_f16(
                    __builtin_bit_cast(half8, kr[s]),
                    __builtin_bit_cast(half8, gr[s]), acc, 0, 0, 0);
        }

        // ---- M -> LDS; agg atomics (ends acc liveness early) ----
#pragma unroll
        for (int r = 0; r < 16; r++) {
            const int e = (r & 3) + 8 * (r >> 2) + 4 * half;
            Mlds[e * 36 + li] = acc[r];
        }
#pragma unroll
        for (int r = 0; r < 16; r++) {
            const int e = (r & 3) + 8 * (r >> 2) + 4 * half;
            if (base + e < deg) {
                const int rr = rowS[e];
                atomicAdd(&agg[(size_t)rr * 32 + li], acc[r]);
            }
        }
        asm volatile("s_waitcnt lgkmcnt(0)" ::: "memory");

        // ---- T = cm1b + M @ cm1 (C-layout) ----
        floatx16 acc2;
#pragma unroll
        for (int r = 0; r < 16; r++) acc2[r] = cm1bq;
#pragma unroll
        for (int s2 = 0; s2 < 2; s2++) {
            const float* mp = &Mlds[li * 36 + s2 * 16 + half * 8];
            const float4 m0 = *(const float4*)mp;
            const float4 m1 = *(const float4*)(mp + 4);
            half8 a;
            a[0] = (_Float16)m0.x; a[1] = (_Float16)m0.y;
            a[2] = (_Float16)m0.z; a[3] = (_Float16)m0.w;
            a[4] = (_Float16)m1.x; a[5] = (_Float16)m1.y;
            a[6] = (_Float16)m1.z; a[7] = (_Float16)m1.w;
            acc2 = __builtin_amdgcn_mfma_f32_32x32x16_f16(a, cmb[s2], acc2, 0, 0, 0);
        }

        // ---- U = relu(T)*cm2 -> LDS; we = U @ ones + cm2b (3rd MFMA) ----
#pragma unroll
        for (int r = 0; r < 16; r++) {
            const int e = (r & 3) + 8 * (r >> 2) + 4 * half;
            Mlds[e * 36 + li] = fmaxf(acc2[r], 0.f) * cm2q;
        }
        asm volatile("s_waitcnt lgkmcnt(0)" ::: "memory");
        floatx16 acc3;
#pragma unroll
        for (int r = 0; r < 16; r++) acc3[r] = cm2b0;
#pragma unroll
        for (int s2 = 0; s2 < 2; s2++) {
            const float* mp = &Mlds[li * 36 + s2 * 16 + half * 8];
            const float4 m0 = *(const float4*)mp;
            const float4 m1 = *(const float4*)(mp + 4);
            half8 a;
            a[0] = (_Float16)m0.x; a[1] = (_Float16)m0.y;
            a[2] = (_Float16)m0.z; a[3] = (_Float16)m0.w;
            a[4] = (_Float16)m1.x; a[5] = (_Float16)m1.y;
            a[6] = (_Float16)m1.z; a[7] = (_Float16)m1.w;
            acc3 = __builtin_amdgcn_mfma_f32_32x32x16_f16(a, onesb, acc3, 0, 0, 0);
        }

        // ---- dco atomics: we[e] = acc3[r] (uniform over lanes in half) ----
#pragma unroll
        for (int r = 0; r < 16; r++) {
            const int e = (r & 3) + 8 * (r >> 2) + 4 * half;
            if (base + e < deg && li < 3) {
                const int rr = rowS[e];
                const float d = coord[(size_t)rr * 3 + li] - con;
                atomicAdd(&dco[(size_t)rr * 3 + li], d * acc3[r]);
            }
        }
    }
}

// ---------------------------------------------------------------------------
__global__ __launch_bounds__(256) void node_update_kernel(
    float* __restrict__ h, float* __restrict__ agg,
    float* __restrict__ coord, float* __restrict__ dco,
    const float* __restrict__ invc)
{
    int idx = blockIdx.x * 256 + threadIdx.x;
    if (idx < NN * 32) {
        int v = idx >> 5;
        h[idx] = fmaxf(h[idx] + agg[idx] * invc[v], 0.f);
        agg[idx] = 0.f;
    }
    if (idx < NN * 3) {
        coord[idx] += dco[idx] * invc[idx / 3];
        dco[idx] = 0.f;
    }
}

// ---------------------------------------------------------------------------
__global__ __launch_bounds__(256) void final_kernel(
    const float* __restrict__ h, const float* __restrict__ coord,
    const float* __restrict__ wa, const float* __restrict__ ba,
    const float* __restrict__ wb, const float* __restrict__ bb,
    float* __restrict__ out)
{
    const int lane = threadIdx.x & 63;
    const int v = blockIdx.x * 4 + (threadIdx.x >> 6);
    if (v >= NN) return;
    const float hreg = (lane < 32) ? h[(size_t)v * 32 + lane] : 0.f;
    float acc = ba[lane];
#pragma unroll
    for (int f = 0; f < 32; f++) acc += __shfl(hreg, f, 64) * wa[f * 64 + lane];
    float part = fmaxf(acc, 0.f) * wb[lane];
#pragma unroll
    for (int off = 32; off >= 1; off >>= 1) part += __shfl_xor(part, off, 64);
    if (lane == 0) out[v] = part + bb[0];
    if (lane < 3) out[NN + (size_t)v * 3 + lane] = coord[(size_t)v * 3 + lane];
}

// ---------------------------------------------------------------------------
extern "C" void kernel_launch(void* const* d_in, const int* in_sizes, int n_in,
                              void* d_out, int out_size, void* d_ws, size_t ws_size,
                              hipStream_t stream)
{
    const float* x    = (const float*)d_in[0];
    const int*   ei   = (const int*)d_in[1];
    const float* ea   = (const float*)d_in[2];
    const float* ci   = (const float*)d_in[3];
    const float* fc1w = (const float*)d_in[4];
    const float* fc1b = (const float*)d_in[5];
    const float* k1w  = (const float*)d_in[6];
    const float* k1b  = (const float*)d_in[7];
    const float* k2w  = (const float*)d_in[8];
    const float* k2b  = (const float*)d_in[9];
    const float* k3w  = (const float*)d_in[10];
    const float* k3b  = (const float*)d_in[11];
    const float* cm1w = (const float*)d_in[12];
    const float* cm1b = (const float*)d_in[13];
    const float* cm2w = (const float*)d_in[14];
    const float* cm2b = (const float*)d_in[15];
    const float* f2aw = (const float*)d_in[16];
    const float* f2ab = (const float*)d_in[17];
    const float* f2bw = (const float*)d_in[18];
    const float* f2bb = (const float*)d_in[19];

    // ---- workspace carve; tiers: A=(2) fp16 k2, B=(1) u8 k2. G always fp16.
    size_t o_k2, o_k2s, o_G, o_h, o_agg, o_bv, o_coord, o_dco, o_invc, o_rc,
           o_cc, o_cs, o_cn, o_el, o_ri, o_ci, o_w2h;
#define ALGN(v) (((v) + 255) & ~(size_t)255)
    auto carve = [&](size_t k2es) -> size_t {
        size_t o = 0;
        o_k2   = o; o += ALGN((size_t)NE * 256 * k2es);
        o_k2s  = o; o += ALGN((size_t)NE * 4);
        o_G    = o; o += ALGN((size_t)NN * 8192 * 2);
        o_h    = o; o += ALGN((size_t)NN * 32 * 4);
        o_agg  = o; o += ALGN((size_t)NN * 32 * 4);
        o_bv   = o; o += ALGN((size_t)NN * 32 * 4);
        o_coord= o; o += ALGN((size_t)NN * 3 * 4);
        o_dco  = o; o += ALGN((size_t)NN * 3 * 4);
        o_invc = o; o += ALGN((size_t)NN * 4);
        o_rc   = o; o += ALGN((size_t)NN * 4);
        o_cc   = o; o += ALGN((size_t)NN * 4);
        o_cs   = o; o += ALGN((size_t)(NN + 1) * 4);
        o_cn   = o; o += ALGN((size_t)NN * 4);
        o_el   = o; o += ALGN((size_t)NE * 4);
        o_ri   = o; o += ALGN((size_t)NE * 4);
        o_ci   = o; o += ALGN((size_t)NE * 4);
        o_w2h  = o; o += ALGN((size_t)128 * 256 * 2);
        return o;
    };
    int fk2;
    if      (ws_size >= carve(2)) { fk2 = 0; carve(2); }  // ~328 MB
    else if (ws_size >= carve(1)) { fk2 = 1; carve(1); }  // ~251 MB
    else {
        sentinel_kernel<<<(NN * 4 + 255) / 256, 256, 0, stream>>>((float*)d_out, NN * 4, 1.0e6f);
        return;
    }

    char* wsb = (char*)d_ws;
    u8*    k2g   = (u8*)(wsb + o_k2);
    float* k2s   = (float*)(wsb + o_k2s);
    u16*   Gg    = (u16*)(wsb + o_G);
    float* h     = (float*)(wsb + o_h);
    float* agg   = (float*)(wsb + o_agg);
    float* bvec  = (float*)(wsb + o_bv);
    float* coord = (float*)(wsb + o_coord);
    float* dco   = (float*)(wsb + o_dco);
    float* invc  = (float*)(wsb + o_invc);
    int*   rowcnt= (int*)(wsb + o_rc);
    int*   colcnt= (int*)(wsb + o_cc);
    int*   cstart= (int*)(wsb + o_cs);
    int*   cnext = (int*)(wsb + o_cn);
    int*   elist = (int*)(wsb + o_el);
    int*   ridx  = (int*)(wsb + o_ri);
    int*   cidx  = (int*)(wsb + o_ci);
    u16*   w2h   = (u16*)(wsb + o_w2h);

    hipMemsetAsync(agg,    0, (size_t)NN * 32 * 4, stream);
    hipMemsetAsync(dco,    0, (size_t)NN * 3 * 4, stream);
    hipMemsetAsync(rowcnt, 0, (size_t)NN * 4, stream);
    hipMemsetAsync(colcnt, 0, (size_t)NN * 4, stream);

    detect_idx_kernel<<<1, 256, 0, stream>>>(ei, cnext);   // cnext[0] as flag temp
    convert_idx_kernel<<<(2 * NE + 255) / 256, 256, 0, stream>>>(ei, cnext, ridx, cidx);
    init_nodes_kernel<<<(NN * 32 + 255) / 256, 256, 0, stream>>>(x, fc1w, fc1b, ci, h, coord);
    count_kernel<<<(NE + 255) / 256, 256, 0, stream>>>(ridx, cidx, rowcnt, colcnt);
    scan_kernel<<<1, 256, 0, stream>>>(colcnt, rowcnt, cstart, cnext, invc);
    scatter_kernel<<<(NE + 255) / 256, 256, 0, stream>>>(cidx, cnext, elist);
    w2pack_kernel<<<16, 256, 0, stream>>>(k2w, w2h);
    mlp_k2_kernel<<<NE / 32, 256, 0, stream>>>(ea, k1w, k1b, w2h, k2b, k2g, k2s, fk2);

    const dim3 ggrid((NN + 127) / 128, 16);
    for (int l = 0; l < DEPTH; l++) {
        bvec_kernel<<<(NN * 32 + 255) / 256, 256, 0, stream>>>(h, k3b, bvec);
        g_kernel<<<ggrid, 256, 0, stream>>>(h, k3w, Gg);
        edge_kernel<<<(NN + 3) / 4, 256, 0, stream>>>(cstart, elist, ridx, k2g, k2s,
                                                      Gg, coord, cm1w, cm1b, cm2w, cm2b,
                                                      bvec, agg, dco, fk2);
        node_update_kernel<<<(NN * 32 + 255) / 256, 256, 0, stream>>>(h, agg, coord, dco, invc);
    }
    final_kernel<<<(NN + 3) / 4, 256, 0, stream>>>(h, coord, f2aw, f2ab, f2bw, f2bb,
                                                   (float*)d_out);
}

// Round 11
// 925.587 us; speedup vs baseline: 2.2614x; 1.0414x over previous
//
#include <hip/hip_runtime.h>

// EGKN: E(n) graph kernel network.
#define NN 10000      // nodes
#define NE 300000     // edges
#define DEPTH 4

typedef unsigned int   u32;
typedef unsigned short u16;
typedef unsigned char  u8;

typedef _Float16 half8  __attribute__((ext_vector_type(8)));
typedef _Float16 half2t __attribute__((ext_vector_type(2)));
typedef float  floatx16 __attribute__((ext_vector_type(16)));

__device__ __forceinline__ u32 f2h(float f) {
    f = fminf(fmaxf(f, -60000.f), 60000.f);
    _Float16 h = (_Float16)f;
    return (u32)__builtin_bit_cast(u16, h);
}
__device__ __forceinline__ float h2f(u16 b) {
    return (float)__builtin_bit_cast(_Float16, b);
}

// ---------------------------------------------------------------------------
__global__ void sentinel_kernel(float* out, int n, float val) {
    int i = blockIdx.x * 256 + threadIdx.x;
    if (i < n) out[i] = val;
}

// ---------------------------------------------------------------------------
__global__ void detect_idx_kernel(const int* __restrict__ ei, int* __restrict__ flag) {
    __shared__ int nz;
    if (threadIdx.x == 0) nz = 0;
    __syncthreads();
    if (ei[threadIdx.x * 2 + 1] != 0) atomicAdd(&nz, 1);
    __syncthreads();
    if (threadIdx.x == 0) *flag = (nz == 0) ? 1 : 0;   // 1 => int64
}

__global__ __launch_bounds__(256) void convert_idx_kernel(
    const int* __restrict__ ei, const int* __restrict__ flag,
    int* __restrict__ ridx, int* __restrict__ cidx)
{
    int e = blockIdx.x * 256 + threadIdx.x;
    if (e >= 2 * NE) return;
    const int is64 = *flag;
    int v = is64 ? ei[2 * e] : ei[e];
    if (e < NE) ridx[e] = v; else cidx[e - NE] = v;
}

// ---------------------------------------------------------------------------
__global__ __launch_bounds__(256) void init_nodes_kernel(
    const float* __restrict__ x, const float* __restrict__ fc1w,
    const float* __restrict__ fc1b, const float* __restrict__ ci,
    float* __restrict__ h, float* __restrict__ coord)
{
    int idx = blockIdx.x * 256 + threadIdx.x;
    if (idx < NN * 32) {
        int v = idx >> 5, f = idx & 31;
        float acc = fc1b[f];
#pragma unroll
        for (int i = 0; i < 3; i++) acc += x[v * 3 + i] * fc1w[i * 32 + f];
        h[idx] = acc;
    }
    if (idx < NN * 3) coord[idx] = ci[idx];
}

// ---------------------------------------------------------------------------
__global__ __launch_bounds__(256) void count_kernel(
    const int* __restrict__ ridx, const int* __restrict__ cidx,
    int* __restrict__ rowcnt, int* __restrict__ colcnt)
{
    int e = blockIdx.x * 256 + threadIdx.x;
    if (e < NE) { atomicAdd(&rowcnt[ridx[e]], 1); atomicAdd(&colcnt[cidx[e]], 1); }
}

// scan col CSR always; row CSR when mode==1; invc from rowcnt
__global__ void scan_kernel(const int* __restrict__ colcnt, const int* __restrict__ rowcnt,
                            int* __restrict__ cstart, int* __restrict__ cnext,
                            int* __restrict__ rstart, int* __restrict__ rnext,
                            float* __restrict__ invc, int mode)
{
    __shared__ int partC[256], partR[256];
    const int t = threadIdx.x;
    int sumC = 0, sumR = 0;
    for (int i = 0; i < 40; i++) {
        int v = t * 40 + i;
        if (v < NN) { sumC += colcnt[v]; sumR += rowcnt[v]; }
    }
    partC[t] = sumC; partR[t] = sumR;
    __syncthreads();
    if (t == 0) {
        int rc = 0, rr = 0;
        for (int i = 0; i < 256; i++) {
            int tc = partC[i]; partC[i] = rc; rc += tc;
            int tr = partR[i]; partR[i] = rr; rr += tr;
        }
    }
    __syncthreads();
    int runC = partC[t], runR = partR[t];
    for (int i = 0; i < 40; i++) {
        int v = t * 40 + i;
        if (v < NN) {
            cstart[v] = runC; cnext[v] = runC; runC += colcnt[v];
            if (mode) { rstart[v] = runR; rnext[v] = runR; runR += rowcnt[v]; }
        }
    }
    if (t == 255) { cstart[NN] = runC; if (mode) rstart[NN] = runR; }
    for (int v = t; v < NN; v += 256) invc[v] = 1.0f / fmaxf((float)rowcnt[v], 1.0f);
}

__global__ __launch_bounds__(256) void scatter_kernel(
    const int* __restrict__ cidx, const int* __restrict__ ridx,
    int* __restrict__ cnext, int* __restrict__ rnext,
    int* __restrict__ elist, int* __restrict__ rpos, int* __restrict__ rcol,
    int mode)
{
    int e = blockIdx.x * 256 + threadIdx.x;
    if (e >= NE) return;
    int pos = atomicAdd(&cnext[cidx[e]], 1);
    elist[pos] = e;
    if (mode) {
        int rp = atomicAdd(&rnext[ridx[e]], 1);
        rpos[e] = rp;
        rcol[rp] = cidx[e];
    }
}

// ---------------------------------------------------------------------------
// w2 -> fp16 MFMA B-fragment pack (one-time, 64 KB)
// ---------------------------------------------------------------------------
__global__ __launch_bounds__(256) void w2pack_kernel(
    const float* __restrict__ w2, u16* __restrict__ w2h)
{
    const int slot = blockIdx.x * 256 + threadIdx.x;    // 0..4095
    const int c = slot >> 9, s = (slot >> 6) & 7, l = slot & 63;
    const int li = l & 31, hf = l >> 5;
    const int k0 = s * 16 + hf * 8, col = c * 32 + li;
    u32 pk[8];
#pragma unroll
    for (int j = 0; j < 8; j++) pk[j] = f2h(w2[(size_t)(k0 + j) * 256 + col]);
    uint4 o;
    o.x = pk[0] | (pk[1] << 16);
    o.y = pk[2] | (pk[3] << 16);
    o.z = pk[4] | (pk[5] << 16);
    o.w = pk[6] | (pk[7] << 16);
    *(uint4*)&w2h[(size_t)slot * 8] = o;
}

// cm1 -> fp16 B-fragment pack (2 KB): cmpk[(s2*64+l)*8+j] = cm1[(s2*16+(l>>5)*8+j)][l&31]
__global__ void cm1pack_kernel(const float* __restrict__ cm1w, u16* __restrict__ cmpk)
{
    const int t = threadIdx.x;
    if (t >= 128) return;
    const int s2 = t >> 6, l = t & 63, li = l & 31, hf = l >> 5;
    u32 pk[8];
#pragma unroll
    for (int j = 0; j < 8; j++) pk[j] = f2h(cm1w[(s2 * 16 + hf * 8 + j) * 32 + li]);
    uint4 o;
    o.x = pk[0] | (pk[1] << 16);
    o.y = pk[2] | (pk[3] << 16);
    o.z = pk[4] | (pk[5] << 16);
    o.w = pk[6] | (pk[7] << 16);
    *(uint4*)&cmpk[(size_t)(s2 * 64 + l) * 8] = o;
}

// ---------------------------------------------------------------------------
// k2 MLP: edge_attr[6] -> 128 -> 256 (relu both). 32 edges/block.
// k2 stored u8 [e][256] + per-edge scale k2s[e] (ws bracket => always u8 tier).
// ---------------------------------------------------------------------------
__global__ __launch_bounds__(256) void mlp_k2_kernel(
    const float* __restrict__ ea,
    const float* __restrict__ w1, const float* __restrict__ b1,
    const u16* __restrict__ w2h, const float* __restrict__ b2,
    u8* __restrict__ k2base, float* __restrict__ k2s)
{
    __shared__ __align__(16) float ea_s[32 * 6];
    __shared__ __align__(16) u16   k1f[4096];          // A-frags: [s][lane][j]
    __shared__ __align__(16) float M_s[32 * 260];      // [e][c], padded
    const int t  = threadIdx.x;
    const int e0 = blockIdx.x * 32;

    for (int idx = t; idx < 192; idx += 256)
        ea_s[idx] = ea[(size_t)e0 * 6 + idx];
    __syncthreads();

    // layer 1: [32,6]@[6,128] relu -> fp16 fragments
    for (int slot = t; slot < 512; slot += 256) {
        const int s  = slot >> 6;
        const int l  = slot & 63;
        const int li = l & 31, hf = l >> 5;
        const int k0 = s * 16 + hf * 8;
        float acc[8];
        {
            const float4 ba = *(const float4*)&b1[k0];
            const float4 bb = *(const float4*)&b1[k0 + 4];
            acc[0] = ba.x; acc[1] = ba.y; acc[2] = ba.z; acc[3] = ba.w;
            acc[4] = bb.x; acc[5] = bb.y; acc[6] = bb.z; acc[7] = bb.w;
        }
#pragma unroll
        for (int i = 0; i < 6; i++) {
            const float ev = ea_s[li * 6 + i];
            const float4 wa = *(const float4*)&w1[i * 128 + k0];
            const float4 wb = *(const float4*)&w1[i * 128 + k0 + 4];
            acc[0] += ev * wa.x; acc[1] += ev * wa.y;
            acc[2] += ev * wa.z; acc[3] += ev * wa.w;
            acc[4] += ev * wb.x; acc[5] += ev * wb.y;
            acc[6] += ev * wb.z; acc[7] += ev * wb.w;
        }
        uint4 o;
        o.x = f2h(fmaxf(acc[0], 0.f)) | (f2h(fmaxf(acc[1], 0.f)) << 16);
        o.y = f2h(fmaxf(acc[2], 0.f)) | (f2h(fmaxf(acc[3], 0.f)) << 16);
        o.z = f2h(fmaxf(acc[4], 0.f)) | (f2h(fmaxf(acc[5], 0.f)) << 16);
        o.w = f2h(fmaxf(acc[6], 0.f)) | (f2h(fmaxf(acc[7], 0.f)) << 16);
        *(uint4*)&k1f[slot * 8] = o;
    }
    __syncthreads();

    // layer 2: [32,128]@[128,256] via mfma_32x32x16_f16
    {
        const int w  = t >> 6, l = t & 63;
        const int li = l & 31, hf = l >> 5;
#pragma unroll
        for (int ct = 0; ct < 2; ct++) {
            const int c = w * 2 + ct;
            floatx16 acc;
#pragma unroll
            for (int r = 0; r < 16; r++) acc[r] = 0.f;
#pragma unroll
            for (int s = 0; s < 8; s++) {
                const half8 a = __builtin_bit_cast(half8,
                    *(const uint4*)&k1f[(s * 64 + l) * 8]);
                const half8 b = __builtin_bit_cast(half8,
                    *(const uint4*)&w2h[(((size_t)c * 8 + s) * 64 + l) * 8]);
                acc = __builtin_amdgcn_mfma_f32_32x32x16_f16(a, b, acc, 0, 0, 0);
            }
            const float bb = b2[c * 32 + li];
#pragma unroll
            for (int r = 0; r < 16; r++) {
                const int e = (r & 3) + 8 * (r >> 2) + 4 * hf;
                M_s[e * 260 + c * 32 + li] = fmaxf(acc[r] + bb, 0.f);
            }
        }
    }
    __syncthreads();

    // store k2 u8: thread t -> edge el=t>>3, col-chunk q=t&7 (32 cols each)
    {
        const int el = t >> 3, q = t & 7;
        const size_t eglob = (size_t)e0 + el;
        float mx = 0.f;
#pragma unroll
        for (int u = 0; u < 32; u++) mx = fmaxf(mx, M_s[el * 260 + q * 32 + u]);
        mx = fmaxf(mx, __shfl_xor(mx, 1, 8));
        mx = fmaxf(mx, __shfl_xor(mx, 2, 8));
        mx = fmaxf(mx, __shfl_xor(mx, 4, 8));
        const float sc  = mx / 255.f;
        const float inv = (mx > 0.f) ? 255.f / mx : 0.f;
        if (q == 0) k2s[eglob] = sc;
        u8* outp = k2base + eglob * 256 + q * 32;
        u32 w[8];
#pragma unroll
        for (int u = 0; u < 8; u++) {
            float4 a = *(float4*)&M_s[el * 260 + q * 32 + u * 4];
            u32 q0 = (u32)fminf(rintf(a.x * inv), 255.f);
            u32 q1 = (u32)fminf(rintf(a.y * inv), 255.f);
            u32 q2 = (u32)fminf(rintf(a.z * inv), 255.f);
            u32 q3 = (u32)fminf(rintf(a.w * inv), 255.f);
            w[u] = q0 | (q1 << 8) | (q2 << 16) | (q3 << 24);
        }
        *(uint4*)outp        = make_uint4(w[0], w[1], w[2], w[3]);
        *(uint4*)(outp + 16) = make_uint4(w[4], w[5], w[6], w[7]);
    }
}

// ---------------------------------------------------------------------------
__global__ __launch_bounds__(256) void bvec_kernel(
    const float* __restrict__ h, const float* __restrict__ b3, float* __restrict__ bvec)
{
    int idx = blockIdx.x * 256 + threadIdx.x;
    if (idx >= NN * 32) return;
    int v = idx >> 5, i = idx & 31;
    const float* hp = &h[(size_t)v * 32];
    const float* bp = &b3[i * 32];
    float acc = 0.f;
#pragma unroll
    for (int c = 0; c < 8; c++) {
        float4 hv = *(const float4*)&hp[c * 4];
        float4 bv = *(const float4*)&bp[c * 4];
        acc += hv.x * bv.x + hv.y * bv.y + hv.z * bv.z + hv.w * bv.w;
    }
    bvec[idx] = acc;
}

// ---------------------------------------------------------------------------
// G in MFMA-B-fragment order, fp16. LDS h staging in packed fp16 + fdot2.
// ---------------------------------------------------------------------------
__global__ __launch_bounds__(256) void g_kernel(
    const float* __restrict__ h, const float* __restrict__ w3,
    u16* __restrict__ Gg)
{
    __shared__ __align__(16) u32 h16[128 * 16];   // fp16 pairs of h, 8 KB
    const int t  = threadIdx.x;
    const int v0 = blockIdx.x * 128;

    {
        const int v = t >> 1, hh = t & 1;
        float4 a = make_float4(0.f, 0.f, 0.f, 0.f), b = a, c = a, d = a;
        if (v0 + v < NN) {
            const float* hp = &h[(size_t)(v0 + v) * 32 + hh * 16];
            a = *(const float4*)hp;       b = *(const float4*)(hp + 4);
            c = *(const float4*)(hp + 8); d = *(const float4*)(hp + 12);
        }
        uint4 o0, o1;
        o0.x = f2h(a.x) | (f2h(a.y) << 16);
        o0.y = f2h(a.z) | (f2h(a.w) << 16);
        o0.z = f2h(b.x) | (f2h(b.y) << 16);
        o0.w = f2h(b.z) | (f2h(b.w) << 16);
        o1.x = f2h(c.x) | (f2h(c.y) << 16);
        o1.y = f2h(c.z) | (f2h(c.w) << 16);
        o1.z = f2h(d.x) | (f2h(d.y) << 16);
        o1.w = f2h(d.z) | (f2h(d.w) << 16);
        *(uint4*)&h16[v * 16 + hh * 8]     = o0;
        *(uint4*)&h16[v * 16 + hh * 8 + 4] = o1;
    }
    __syncthreads();

    const int by    = blockIdx.y;        // step s, 0..15
    const int lane  = t >> 2;            // 0..63
    const int i     = lane & 31;
    const int halfk = lane >> 5;
    const int j0    = (t & 3) * 2;
    const int k0    = by * 16 + halfk * 8 + j0;

    u32 w0p[16], w1p[16];
    {
        const float* wp0 = &w3[(size_t)k0 * 1024 + (size_t)i * 32];
        const float* wp1 = wp0 + 1024;
#pragma unroll
        for (int c = 0; c < 8; c++) {
            const float4 a = *(const float4*)&wp0[c * 4];
            w0p[c * 2]     = f2h(a.x) | (f2h(a.y) << 16);
            w0p[c * 2 + 1] = f2h(a.z) | (f2h(a.w) << 16);
            const float4 b = *(const float4*)&wp1[c * 4];
            w1p[c * 2]     = f2h(b.x) | (f2h(b.y) << 16);
            w1p[c * 2 + 1] = f2h(b.z) | (f2h(b.w) << 16);
        }
    }
    const int vmax = min(128, NN - v0);
    u32* outp = (u32*)Gg;
#pragma unroll 2
    for (int v = 0; v < vmax; v++) {
        float a0 = 0.f, a1 = 0.f;
#pragma unroll
        for (int c = 0; c < 4; c++) {
            const uint4 q = *(const uint4*)&h16[v * 16 + c * 4];
            const half2t h0 = __builtin_bit_cast(half2t, q.x);
            const half2t h1 = __builtin_bit_cast(half2t, q.y);
            const half2t h2 = __builtin_bit_cast(half2t, q.z);
            const half2t h3 = __builtin_bit_cast(half2t, q.w);
            a0 = __builtin_amdgcn_fdot2(h0, __builtin_bit_cast(half2t, w0p[c*4+0]), a0, false);
            a0 = __builtin_amdgcn_fdot2(h1, __builtin_bit_cast(half2t, w0p[c*4+1]), a0, false);
            a0 = __builtin_amdgcn_fdot2(h2, __builtin_bit_cast(half2t, w0p[c*4+2]), a0, false);
            a0 = __builtin_amdgcn_fdot2(h3, __builtin_bit_cast(half2t, w0p[c*4+3]), a0, false);
            a1 = __builtin_amdgcn_fdot2(h0, __builtin_bit_cast(half2t, w1p[c*4+0]), a1, false);
            a1 = __builtin_amdgcn_fdot2(h1, __builtin_bit_cast(half2t, w1p[c*4+1]), a1, false);
            a1 = __builtin_amdgcn_fdot2(h2, __builtin_bit_cast(half2t, w1p[c*4+2]), a1, false);
            a1 = __builtin_amdgcn_fdot2(h3, __builtin_bit_cast(half2t, w1p[c*4+3]), a1, false);
        }
        outp[(size_t)(v0 + v) * 4096 + by * 256 + t] = f2h(a0) | (f2h(a1) << 16);
    }
}

// ---------------------------------------------------------------------------
// MFMA edge pass. One wave64 per col-node n; 4 waves/block.
// mode 0: agg/dco atomics (fallback). mode 1: atomic-free — m -> mbuf[rpos],
// we -> webuf[rpos] (row-CSR slots), consumed by node_update2.
// Mlds stride 34 (2-way bank aliasing = free; the r10 stride-36 was 8-way).
// C/D layout: col = lane&31, row = (reg&3)+8*(reg>>2)+4*(lane>>5).
// ---------------------------------------------------------------------------
__global__ __launch_bounds__(256) void edge_kernel(
    const int* __restrict__ cstart, const int* __restrict__ elist,
    const int* __restrict__ ridx, const int* __restrict__ rpos,
    const u8* __restrict__ k2base, const float* __restrict__ k2s,
    const u16* __restrict__ Gg, const float* __restrict__ coord,
    const u16* __restrict__ cmpk, const float* __restrict__ cm1b,
    const float* __restrict__ cm2w, const float* __restrict__ cm2b,
    const float* __restrict__ bvec,
    float* __restrict__ agg, float* __restrict__ dco,
    u16* __restrict__ mbuf, u16* __restrict__ webuf, int mode)
{
    const int t    = threadIdx.x;
    const int w    = t >> 6;
    const int l    = t & 63;
    const int li   = l & 31;
    const int half = l >> 5;

    __shared__ __align__(16) float Mlds_all[4][32 * 34];
    __shared__ int idxS_all[4][32];
    float* Mlds = Mlds_all[w];
    int*   idxS = idxS_all[w];      // row (mode 0) or rpos (mode 1) per edge slot

    const int n = blockIdx.x * 4 + w;
    if (n >= NN) return;
    const int s0  = cstart[n];
    const int deg = cstart[n + 1] - s0;
    if (deg == 0) return;

    half8 cmb[2];
    cmb[0] = __builtin_bit_cast(half8, *(const uint4*)&cmpk[(size_t)(0 * 64 + l) * 8]);
    cmb[1] = __builtin_bit_cast(half8, *(const uint4*)&cmpk[(size_t)(1 * 64 + l) * 8]);
    half8 onesb;
#pragma unroll
    for (int j = 0; j < 8; j++) onesb[j] = (_Float16)1.0f;
    const float cm1bq = cm1b[li];
    const float cm2q  = cm2w[li];
    const float cm2b0 = cm2b[0];
    const float bv    = bvec[n * 32 + li];
    const float con   = (mode == 0 && li < 3) ? coord[(size_t)n * 3 + li] : 0.f;
    const u16* Gn = Gg + (size_t)n * 8192;

    for (int base = 0; base < deg; base += 32) {
        const int mye   = base + li;
        const int valid = (mye < deg) ? 1 : 0;
        const int eid   = valid ? elist[s0 + mye] : 0;
        if (l < 32) idxS[l] = valid ? (mode ? rpos[eid] : ridx[eid]) : 0;

        // preload all fragments (32 vmem ops in flight)
        uint4 gr[16];
#pragma unroll
        for (int s = 0; s < 16; s++)
            gr[s] = *(const uint4*)(Gn + s * 512 + l * 8);
        const float se = valid ? k2s[eid] : 0.f;
        const u8* k2row = k2base + (size_t)eid * 256 + half * 8;
        uint2 kr[16];
#pragma unroll
        for (int s = 0; s < 16; s++) kr[s] = *(const uint2*)(k2row + s * 16);

        floatx16 acc;
#pragma unroll
        for (int r = 0; r < 16; r++) acc[r] = bv;
#pragma unroll
        for (int s = 0; s < 16; s++) {
            half8 a;
#pragma unroll
            for (int j = 0; j < 4; j++) {
                a[j]     = (_Float16)((float)((kr[s].x >> (8 * j)) & 0xffu) * se);
                a[4 + j] = (_Float16)((float)((kr[s].y >> (8 * j)) & 0xffu) * se);
            }
            acc = __builtin_amdgcn_mfma_f32_32x32x16_f16(
                a, __builtin_bit_cast(half8, gr[s]), acc, 0, 0, 0);
        }

        // M -> LDS (stride 34); h-scatter (atomic or store)
#pragma unroll
        for (int r = 0; r < 16; r++) {
            const int e = (r & 3) + 8 * (r >> 2) + 4 * half;
            Mlds[e * 34 + li] = acc[r];
        }
        if (mode == 0) {
#pragma unroll
            for (int r = 0; r < 16; r++) {
                const int e = (r & 3) + 8 * (r >> 2) + 4 * half;
                if (base + e < deg)
                    atomicAdd(&agg[(size_t)idxS[e] * 32 + li], acc[r]);
            }
        } else {
#pragma unroll
            for (int r = 0; r < 16; r++) {
                const int e = (r & 3) + 8 * (r >> 2) + 4 * half;
                if (base + e < deg)
                    mbuf[(size_t)idxS[e] * 32 + li] = (u16)f2h(acc[r]);
            }
        }
        asm volatile("s_waitcnt lgkmcnt(0)" ::: "memory");

        // T = cm1b + M @ cm1
        floatx16 acc2;
#pragma unroll
        for (int r = 0; r < 16; r++) acc2[r] = cm1bq;
#pragma unroll
        for (int s2 = 0; s2 < 2; s2++) {
            const float* mp = &Mlds[li * 34 + s2 * 16 + half * 8];
            const float2 m0 = *(const float2*)mp;
            const float2 m1 = *(const float2*)(mp + 2);
            const float2 m2 = *(const float2*)(mp + 4);
            const float2 m3 = *(const float2*)(mp + 6);
            half8 a;
            a[0] = (_Float16)m0.x; a[1] = (_Float16)m0.y;
            a[2] = (_Float16)m1.x; a[3] = (_Float16)m1.y;
            a[4] = (_Float16)m2.x; a[5] = (_Float16)m2.y;
            a[6] = (_Float16)m3.x; a[7] = (_Float16)m3.y;
            acc2 = __builtin_amdgcn_mfma_f32_32x32x16_f16(a, cmb[s2], acc2, 0, 0, 0);
        }

        // U = relu(T)*cm2 -> LDS; we = U @ ones + cm2b
#pragma unroll
        for (int r = 0; r < 16; r++) {
            const int e = (r & 3) + 8 * (r >> 2) + 4 * half;
            Mlds[e * 34 + li] = fmaxf(acc2[r], 0.f) * cm2q;
        }
        asm volatile("s_waitcnt lgkmcnt(0)" ::: "memory");
        floatx16 acc3;
#pragma unroll
        for (int r = 0; r < 16; r++) acc3[r] = cm2b0;
#pragma unroll
        for (int s2 = 0; s2 < 2; s2++) {
            const float* mp = &Mlds[li * 34 + s2 * 16 + half * 8];
            const float2 m0 = *(const float2*)mp;
            const float2 m1 = *(const float2*)(mp + 2);
            const float2 m2 = *(const float2*)(mp + 4);
            const float2 m3 = *(const float2*)(mp + 6);
            half8 a;
            a[0] = (_Float16)m0.x; a[1] = (_Float16)m0.y;
            a[2] = (_Float16)m1.x; a[3] = (_Float16)m1.y;
            a[4] = (_Float16)m2.x; a[5] = (_Float16)m2.y;
            a[6] = (_Float16)m3.x; a[7] = (_Float16)m3.y;
            acc3 = __builtin_amdgcn_mfma_f32_32x32x16_f16(a, onesb, acc3, 0, 0, 0);
        }

        if (mode == 0) {
#pragma unroll
            for (int r = 0; r < 16; r++) {
                const int e = (r & 3) + 8 * (r >> 2) + 4 * half;
                if (base + e < deg && li < 3) {
                    const int rr = idxS[e];
                    const float d = coord[(size_t)rr * 3 + li] - con;
                    atomicAdd(&dco[(size_t)rr * 3 + li], d * acc3[r]);
                }
            }
        } else {
#pragma unroll
            for (int r = 0; r < 16; r++) {
                const int e = (r & 3) + 8 * (r >> 2) + 4 * half;
                if (base + e < deg && li == 0)
                    webuf[idxS[e]] = (u16)f2h(acc3[r]);
            }
        }
    }
}

// ---------------------------------------------------------------------------
// mode 0 node update (atomic fallback)
// ---------------------------------------------------------------------------
__global__ __launch_bounds__(256) void node_update_kernel(
    float* __restrict__ h, float* __restrict__ agg,
    float* __restrict__ coord, float* __restrict__ dco,
    const float* __restrict__ invc)
{
    int idx = blockIdx.x * 256 + threadIdx.x;
    if (idx < NN * 32) {
        int v = idx >> 5;
        h[idx] = fmaxf(h[idx] + agg[idx] * invc[v], 0.f);
        agg[idx] = 0.f;
    }
    if (idx < NN * 3) {
        coord[idx] += dco[idx] * invc[idx / 3];
        dco[idx] = 0.f;
    }
}

// ---------------------------------------------------------------------------
// mode 1 node update: coalesced row-CSR sums of mbuf/webuf; coord ping-pong.
// One wave per node (4 waves/block).
// ---------------------------------------------------------------------------
__global__ __launch_bounds__(256) void node_update2_kernel(
    float* __restrict__ h, const float* __restrict__ coordCur,
    float* __restrict__ coordNew, const u16* __restrict__ mbuf,
    const u16* __restrict__ webuf, const int* __restrict__ rcol,
    const int* __restrict__ rstart, const float* __restrict__ invc)
{
    const int t = threadIdx.x, w = t >> 6, l = t & 63;
    const int li = l & 31, half = l >> 5;
    const int v = blockIdx.x * 4 + w;
    if (v >= NN) return;
    const int s0 = rstart[v], s1 = rstart[v + 1];
    const float iv = invc[v];

    // h: sum m rows (2 slots/iter across halves)
    float acc = 0.f;
    for (int s = s0 + half; s < s1; s += 2)
        acc += h2f(mbuf[(size_t)s * 32 + li]);
    acc += __shfl_xor(acc, 32, 64);
    if (half == 0)
        h[(size_t)v * 32 + li] = fmaxf(h[(size_t)v * 32 + li] + acc * iv, 0.f);

    // coord: sum (coord[v]-coord[col])*we
    const float c0 = coordCur[(size_t)v * 3 + 0];
    const float c1 = coordCur[(size_t)v * 3 + 1];
    const float c2 = coordCur[(size_t)v * 3 + 2];
    float p0 = 0.f, p1 = 0.f, p2 = 0.f;
    for (int s = s0 + l; s < s1; s += 64) {
        const float we = h2f(webuf[s]);
        const int col = rcol[s];
        p0 += (c0 - coordCur[(size_t)col * 3 + 0]) * we;
        p1 += (c1 - coordCur[(size_t)col * 3 + 1]) * we;
        p2 += (c2 - coordCur[(size_t)col * 3 + 2]) * we;
    }
#pragma unroll
    for (int off = 32; off >= 1; off >>= 1) {
        p0 += __shfl_xor(p0, off, 64);
        p1 += __shfl_xor(p1, off, 64);
        p2 += __shfl_xor(p2, off, 64);
    }
    if (l == 0) {
        coordNew[(size_t)v * 3 + 0] = c0 + p0 * iv;
        coordNew[(size_t)v * 3 + 1] = c1 + p1 * iv;
        coordNew[(size_t)v * 3 + 2] = c2 + p2 * iv;
    }
}

// ---------------------------------------------------------------------------
__global__ __launch_bounds__(256) void final_kernel(
    const float* __restrict__ h, const float* __restrict__ coord,
    const float* __restrict__ wa, const float* __restrict__ ba,
    const float* __restrict__ wb, const float* __restrict__ bb,
    float* __restrict__ out)
{
    const int lane = threadIdx.x & 63;
    const int v = blockIdx.x * 4 + (threadIdx.x >> 6);
    if (v >= NN) return;
    const float hreg = (lane < 32) ? h[(size_t)v * 32 + lane] : 0.f;
    float acc = ba[lane];
#pragma unroll
    for (int f = 0; f < 32; f++) acc += __shfl(hreg, f, 64) * wa[f * 64 + lane];
    float part = fmaxf(acc, 0.f) * wb[lane];
#pragma unroll
    for (int off = 32; off >= 1; off >>= 1) part += __shfl_xor(part, off, 64);
    if (lane == 0) out[v] = part + bb[0];
    if (lane < 3) out[NN + (size_t)v * 3 + lane] = coord[(size_t)v * 3 + lane];
}

// ---------------------------------------------------------------------------
extern "C" void kernel_launch(void* const* d_in, const int* in_sizes, int n_in,
                              void* d_out, int out_size, void* d_ws, size_t ws_size,
                              hipStream_t stream)
{
    const float* x    = (const float*)d_in[0];
    const int*   ei   = (const int*)d_in[1];
    const float* ea   = (const float*)d_in[2];
    const float* ci   = (const float*)d_in[3];
    const float* fc1w = (const float*)d_in[4];
    const float* fc1b = (const float*)d_in[5];
    const float* k1w  = (const float*)d_in[6];
    const float* k1b  = (const float*)d_in[7];
    const float* k2w  = (const float*)d_in[8];
    const float* k2b  = (const float*)d_in[9];
    const float* k3w  = (const float*)d_in[10];
    const float* k3b  = (const float*)d_in[11];
    const float* cm1w = (const float*)d_in[12];
    const float* cm1b = (const float*)d_in[13];
    const float* cm2w = (const float*)d_in[14];
    const float* cm2b = (const float*)d_in[15];
    const float* f2aw = (const float*)d_in[16];
    const float* f2ab = (const float*)d_in[17];
    const float* f2bw = (const float*)d_in[18];
    const float* f2bb = (const float*)d_in[19];

    // ws bracket established: ws in [250 MB, 328 MB). k2 always u8.
    // mode 1 (atomic-free) iff the larger carve fits; else mode 0 (r10 path).
    size_t o_k2, o_k2s, o_G, o_h, o_bv, o_coA, o_coB, o_invc, o_rc, o_cc,
           o_cs, o_rs, o_cn, o_rn, o_el, o_w2h, o_cmpk, o_agg, o_dco,
           o_ri, o_ci, o_rp, o_rcl, o_mb, o_wb;
#define ALGN(v) (((v) + 255) & ~(size_t)255)
    auto carve = [&](int mode) -> size_t {
        size_t o = 0;
        o_k2  = o; o += ALGN((size_t)NE * 256);
        o_k2s = o; o += ALGN((size_t)NE * 4);
        o_G   = o; o += ALGN((size_t)NN * 8192 * 2);
        o_h   = o; o += ALGN((size_t)NN * 32 * 4);
        o_bv  = o; o += ALGN((size_t)NN * 32 * 4);
        o_coA = o; o += ALGN((size_t)NN * 3 * 4);
        o_invc= o; o += ALGN((size_t)NN * 4);
        o_rc  = o; o += ALGN((size_t)NN * 4);
        o_cc  = o; o += ALGN((size_t)NN * 4);
        o_cs  = o; o += ALGN((size_t)(NN + 1) * 4);
        o_cn  = o; o += ALGN((size_t)NN * 4);
        o_el  = o; o += ALGN((size_t)NE * 4);
        o_w2h = o; o += ALGN((size_t)128 * 256 * 2);
        o_cmpk= o; o += ALGN((size_t)1024 * 2);
        if (mode == 0) {
            o_agg = o; o += ALGN((size_t)NN * 32 * 4);
            o_dco = o; o += ALGN((size_t)NN * 3 * 4);
            o_ri  = o; o += ALGN((size_t)NE * 4);
            o_ci  = o; o += ALGN((size_t)NE * 4);
            o_coB = o_coA; o_rs = o_cs; o_rn = o_cn;
            o_rp = o_el; o_rcl = o_el; o_mb = o_k2; o_wb = o_k2;   // unused dummies
        } else {
            o_coB = o; o += ALGN((size_t)NN * 3 * 4);
            o_rs  = o; o += ALGN((size_t)(NN + 1) * 4);
            o_rn  = o; o += ALGN((size_t)NN * 4);
            o_rp  = o; o += ALGN((size_t)NE * 4);
            o_rcl = o; o += ALGN((size_t)NE * 4);
            // union: setup {ridx,cidx} vs layers {mbuf,webuf}
            const size_t u = o;
            o_ri = u; o_ci = u + ALGN((size_t)NE * 4);
            o_mb = u; o_wb = u + ALGN((size_t)NE * 32 * 2);
            const size_t setup_sz = 2 * ALGN((size_t)NE * 4);
            const size_t layer_sz = ALGN((size_t)NE * 32 * 2) + ALGN((size_t)NE * 2);
            o += (setup_sz > layer_sz) ? setup_sz : layer_sz;
            o_agg = o_k2; o_dco = o_k2;                            // unused dummies
        }
        return o;
    };
    int mode = (ws_size >= carve(1)) ? 1 : 0;
    size_t need = carve(mode);   // re-carve to set offsets for chosen mode
    if (ws_size < need) {
        sentinel_kernel<<<(NN * 4 + 255) / 256, 256, 0, stream>>>((float*)d_out, NN * 4, 1.0e6f);
        return;
    }

    char* wsb = (char*)d_ws;
    u8*    k2g   = (u8*)(wsb + o_k2);
    float* k2s   = (float*)(wsb + o_k2s);
    u16*   Gg    = (u16*)(wsb + o_G);
    float* h     = (float*)(wsb + o_h);
    float* bvec  = (float*)(wsb + o_bv);
    float* coA   = (float*)(wsb + o_coA);
    float* coB   = (float*)(wsb + o_coB);
    float* invc  = (float*)(wsb + o_invc);
    int*   rowcnt= (int*)(wsb + o_rc);
    int*   colcnt= (int*)(wsb + o_cc);
    int*   cstart= (int*)(wsb + o_cs);
    int*   rstart= (int*)(wsb + o_rs);
    int*   cnext = (int*)(wsb + o_cn);
    int*   rnext = (int*)(wsb + o_rn);
    int*   elist = (int*)(wsb + o_el);
    u16*   w2h   = (u16*)(wsb + o_w2h);
    u16*   cmpk  = (u16*)(wsb + o_cmpk);
    float* agg   = (float*)(wsb + o_agg);
    float* dco   = (float*)(wsb + o_dco);
    int*   ridx  = (int*)(wsb + o_ri);
    int*   cidx  = (int*)(wsb + o_ci);
    int*   rpos  = (int*)(wsb + o_rp);
    int*   rcol  = (int*)(wsb + o_rcl);
    u16*   mbuf  = (u16*)(wsb + o_mb);
    u16*   webuf = (u16*)(wsb + o_wb);

    hipMemsetAsync(rowcnt, 0, (size_t)NN * 4, stream);
    hipMemsetAsync(colcnt, 0, (size_t)NN * 4, stream);
    if (mode == 0) {
        hipMemsetAsync(agg, 0, (size_t)NN * 32 * 4, stream);
        hipMemsetAsync(dco, 0, (size_t)NN * 3 * 4, stream);
    }

    detect_idx_kernel<<<1, 256, 0, stream>>>(ei, cnext);   // cnext[0] as flag temp
    convert_idx_kernel<<<(2 * NE + 255) / 256, 256, 0, stream>>>(ei, cnext, ridx, cidx);
    init_nodes_kernel<<<(NN * 32 + 255) / 256, 256, 0, stream>>>(x, fc1w, fc1b, ci, h, coA);
    count_kernel<<<(NE + 255) / 256, 256, 0, stream>>>(ridx, cidx, rowcnt, colcnt);
    scan_kernel<<<1, 256, 0, stream>>>(colcnt, rowcnt, cstart, cnext, rstart, rnext,
                                       invc, mode);
    scatter_kernel<<<(NE + 255) / 256, 256, 0, stream>>>(cidx, ridx, cnext, rnext,
                                                         elist, rpos, rcol, mode);
    w2pack_kernel<<<16, 256, 0, stream>>>(k2w, w2h);
    cm1pack_kernel<<<1, 128, 0, stream>>>(cm1w, cmpk);
    mlp_k2_kernel<<<NE / 32, 256, 0, stream>>>(ea, k1w, k1b, w2h, k2b, k2g, k2s);

    float* coCur = coA;
    float* coAlt = coB;
    const dim3 ggrid((NN + 127) / 128, 16);
    for (int l = 0; l < DEPTH; l++) {
        bvec_kernel<<<(NN * 32 + 255) / 256, 256, 0, stream>>>(h, k3b, bvec);
        g_kernel<<<ggrid, 256, 0, stream>>>(h, k3w, Gg);
        edge_kernel<<<(NN + 3) / 4, 256, 0, stream>>>(cstart, elist, ridx, rpos,
                                                      k2g, k2s, Gg, coCur, cmpk,
                                                      cm1b, cm2w, cm2b, bvec,
                                                      agg, dco, mbuf, webuf, mode);
        if (mode == 1) {
            node_update2_kernel<<<(NN + 3) / 4, 256, 0, stream>>>(
                h, coCur, coAlt, mbuf, webuf, rcol, rstart, invc);
            float* tmp = coCur; coCur = coAlt; coAlt = tmp;
        } else {
            node_update_kernel<<<(NN * 32 + 255) / 256, 256, 0, stream>>>(
                h, agg, coCur, dco, invc);
        }
    }
    final_kernel<<<(NN + 3) / 4, 256, 0, stream>>>(h, coCur, f2aw, f2ab, f2bw, f2bb,
                                                   (float*)d_out);
}

// Round 13
// 922.124 us; speedup vs baseline: 2.2699x; 1.0038x over previous
//
#include <hip/hip_runtime.h>

// EGKN: E(n) graph kernel network.
#define NN 10000      // nodes
#define NE 300000     // edges
#define DEPTH 4

typedef unsigned int   u32;
typedef unsigned short u16;
typedef unsigned char  u8;

typedef _Float16 half8  __attribute__((ext_vector_type(8)));
typedef _Float16 half2t __attribute__((ext_vector_type(2)));
typedef float  floatx16 __attribute__((ext_vector_type(16)));

__device__ __forceinline__ u32 f2h(float f) {
    f = fminf(fmaxf(f, -60000.f), 60000.f);
    _Float16 h = (_Float16)f;
    return (u32)__builtin_bit_cast(u16, h);
}
__device__ __forceinline__ float h2f(u16 b) {
    return (float)__builtin_bit_cast(_Float16, b);
}

// ---------------------------------------------------------------------------
__global__ void sentinel_kernel(float* out, int n, float val) {
    int i = blockIdx.x * 256 + threadIdx.x;
    if (i < n) out[i] = val;
}

// ---------------------------------------------------------------------------
__global__ void detect_idx_kernel(const int* __restrict__ ei, int* __restrict__ flag) {
    __shared__ int nz;
    if (threadIdx.x == 0) nz = 0;
    __syncthreads();
    if (ei[threadIdx.x * 2 + 1] != 0) atomicAdd(&nz, 1);
    __syncthreads();
    if (threadIdx.x == 0) *flag = (nz == 0) ? 1 : 0;   // 1 => int64
}

__global__ __launch_bounds__(256) void convert_idx_kernel(
    const int* __restrict__ ei, const int* __restrict__ flag,
    int* __restrict__ ridx, int* __restrict__ cidx)
{
    int e = blockIdx.x * 256 + threadIdx.x;
    if (e >= 2 * NE) return;
    const int is64 = *flag;
    int v = is64 ? ei[2 * e] : ei[e];
    if (e < NE) ridx[e] = v; else cidx[e - NE] = v;
}

// ---------------------------------------------------------------------------
__global__ __launch_bounds__(256) void init_nodes_kernel(
    const float* __restrict__ x, const float* __restrict__ fc1w,
    const float* __restrict__ fc1b, const float* __restrict__ ci,
    float* __restrict__ h, float* __restrict__ coord)
{
    int idx = blockIdx.x * 256 + threadIdx.x;
    if (idx < NN * 32) {
        int v = idx >> 5, f = idx & 31;
        float acc = fc1b[f];
#pragma unroll
        for (int i = 0; i < 3; i++) acc += x[v * 3 + i] * fc1w[i * 32 + f];
        h[idx] = acc;
    }
    if (idx < NN * 3) coord[idx] = ci[idx];
}

// ---------------------------------------------------------------------------
__global__ __launch_bounds__(256) void count_kernel(
    const int* __restrict__ ridx, const int* __restrict__ cidx,
    int* __restrict__ rowcnt, int* __restrict__ colcnt)
{
    int e = blockIdx.x * 256 + threadIdx.x;
    if (e < NE) { atomicAdd(&rowcnt[ridx[e]], 1); atomicAdd(&colcnt[cidx[e]], 1); }
}

__global__ void scan_kernel(const int* __restrict__ colcnt, const int* __restrict__ rowcnt,
                            int* __restrict__ cstart, int* __restrict__ cnext,
                            int* __restrict__ rstart, int* __restrict__ rnext,
                            float* __restrict__ invc, int mode)
{
    __shared__ int partC[256], partR[256];
    const int t = threadIdx.x;
    int sumC = 0, sumR = 0;
    for (int i = 0; i < 40; i++) {
        int v = t * 40 + i;
        if (v < NN) { sumC += colcnt[v]; sumR += rowcnt[v]; }
    }
    partC[t] = sumC; partR[t] = sumR;
    __syncthreads();
    if (t == 0) {
        int rc = 0, rr = 0;
        for (int i = 0; i < 256; i++) {
            int tc = partC[i]; partC[i] = rc; rc += tc;
            int tr = partR[i]; partR[i] = rr; rr += tr;
        }
    }
    __syncthreads();
    int runC = partC[t], runR = partR[t];
    for (int i = 0; i < 40; i++) {
        int v = t * 40 + i;
        if (v < NN) {
            cstart[v] = runC; cnext[v] = runC; runC += colcnt[v];
            if (mode) { rstart[v] = runR; rnext[v] = runR; runR += rowcnt[v]; }
        }
    }
    if (t == 255) { cstart[NN] = runC; if (mode) rstart[NN] = runR; }
    for (int v = t; v < NN; v += 256) invc[v] = 1.0f / fmaxf((float)rowcnt[v], 1.0f);
}

__global__ __launch_bounds__(256) void scatter_kernel(
    const int* __restrict__ cidx, const int* __restrict__ ridx,
    int* __restrict__ cnext, int* __restrict__ rnext,
    int* __restrict__ elist, int* __restrict__ rpos, int* __restrict__ rcol,
    int mode)
{
    int e = blockIdx.x * 256 + threadIdx.x;
    if (e >= NE) return;
    int pos = atomicAdd(&cnext[cidx[e]], 1);
    elist[pos] = e;
    if (mode) {
        int rp = atomicAdd(&rnext[ridx[e]], 1);
        rpos[e] = rp;
        rcol[rp] = cidx[e];
    }
}

// ---------------------------------------------------------------------------
// w2 -> fp16 MFMA B-fragment pack (one-time, 64 KB)
// ---------------------------------------------------------------------------
__global__ __launch_bounds__(256) void w2pack_kernel(
    const float* __restrict__ w2, u16* __restrict__ w2h)
{
    const int slot = blockIdx.x * 256 + threadIdx.x;    // 0..4095
    const int c = slot >> 9, s = (slot >> 6) & 7, l = slot & 63;
    const int li = l & 31, hf = l >> 5;
    const int k0 = s * 16 + hf * 8, col = c * 32 + li;
    u32 pk[8];
#pragma unroll
    for (int j = 0; j < 8; j++) pk[j] = f2h(w2[(size_t)(k0 + j) * 256 + col]);
    uint4 o;
    o.x = pk[0] | (pk[1] << 16);
    o.y = pk[2] | (pk[3] << 16);
    o.z = pk[4] | (pk[5] << 16);
    o.w = pk[6] | (pk[7] << 16);
    *(uint4*)&w2h[(size_t)slot * 8] = o;
}

// cm1 -> fp16 B-fragment pack (2 KB)
__global__ void cm1pack_kernel(const float* __restrict__ cm1w, u16* __restrict__ cmpk)
{
    const int t = threadIdx.x;
    if (t >= 128) return;
    const int s2 = t >> 6, l = t & 63, li = l & 31, hf = l >> 5;
    u32 pk[8];
#pragma unroll
    for (int j = 0; j < 8; j++) pk[j] = f2h(cm1w[(s2 * 16 + hf * 8 + j) * 32 + li]);
    uint4 o;
    o.x = pk[0] | (pk[1] << 16);
    o.y = pk[2] | (pk[3] << 16);
    o.z = pk[4] | (pk[5] << 16);
    o.w = pk[6] | (pk[7] << 16);
    *(uint4*)&cmpk[(size_t)(s2 * 64 + l) * 8] = o;
}

// ---------------------------------------------------------------------------
// k2 MLP: edge_attr[6] -> 128 -> 256 (relu both). 32 edges/block, u8 out.
// M_s is fp16 (16.5 KB; block LDS ~26 KB). Epilogue: el=t&31, qq=t>>5 ->
// 2-lanes/bank LDS reads (conflict-free); per-edge max from registers +
// shfl_xor(32) + cross-wave LDS combine.  [kept from r12 — block-local]
// ---------------------------------------------------------------------------
__global__ __launch_bounds__(256) void mlp_k2_kernel(
    const float* __restrict__ ea,
    const float* __restrict__ w1, const float* __restrict__ b1,
    const u16* __restrict__ w2h, const float* __restrict__ b2,
    u8* __restrict__ k2base, float* __restrict__ k2s)
{
    __shared__ __align__(16) float ea_s[32 * 6];
    __shared__ __align__(16) u16   k1f[4096];          // A-frags: [s][lane][j]
    __shared__ __align__(16) u16   M_s[32 * 258];      // [e][c] fp16, stride 258
    __shared__ float pmax_s[4][32];
    const int t  = threadIdx.x;
    const int e0 = blockIdx.x * 32;

    for (int idx = t; idx < 192; idx += 256)
        ea_s[idx] = ea[(size_t)e0 * 6 + idx];
    __syncthreads();

    // layer 1: [32,6]@[6,128] relu -> fp16 fragments
    for (int slot = t; slot < 512; slot += 256) {
        const int s  = slot >> 6;
        const int l  = slot & 63;
        const int li = l & 31, hf = l >> 5;
        const int k0 = s * 16 + hf * 8;
        float acc[8];
        {
            const float4 ba = *(const float4*)&b1[k0];
            const float4 bb = *(const float4*)&b1[k0 + 4];
            acc[0] = ba.x; acc[1] = ba.y; acc[2] = ba.z; acc[3] = ba.w;
            acc[4] = bb.x; acc[5] = bb.y; acc[6] = bb.z; acc[7] = bb.w;
        }
#pragma unroll
        for (int i = 0; i < 6; i++) {
            const float ev = ea_s[li * 6 + i];
            const float4 wa = *(const float4*)&w1[i * 128 + k0];
            const float4 wb = *(const float4*)&w1[i * 128 + k0 + 4];
            acc[0] += ev * wa.x; acc[1] += ev * wa.y;
            acc[2] += ev * wa.z; acc[3] += ev * wa.w;
            acc[4] += ev * wb.x; acc[5] += ev * wb.y;
            acc[6] += ev * wb.z; acc[7] += ev * wb.w;
        }
        uint4 o;
        o.x = f2h(fmaxf(acc[0], 0.f)) | (f2h(fmaxf(acc[1], 0.f)) << 16);
        o.y = f2h(fmaxf(acc[2], 0.f)) | (f2h(fmaxf(acc[3], 0.f)) << 16);
        o.z = f2h(fmaxf(acc[4], 0.f)) | (f2h(fmaxf(acc[5], 0.f)) << 16);
        o.w = f2h(fmaxf(acc[6], 0.f)) | (f2h(fmaxf(acc[7], 0.f)) << 16);
        *(uint4*)&k1f[slot * 8] = o;
    }
    __syncthreads();

    // layer 2: [32,128]@[128,256] via mfma_32x32x16_f16, fp16 to LDS
    {
        const int w  = t >> 6, l = t & 63;
        const int li = l & 31, hf = l >> 5;
#pragma unroll
        for (int ct = 0; ct < 2; ct++) {
            const int c = w * 2 + ct;
            floatx16 acc;
#pragma unroll
            for (int r = 0; r < 16; r++) acc[r] = 0.f;
#pragma unroll
            for (int s = 0; s < 8; s++) {
                const half8 a = __builtin_bit_cast(half8,
                    *(const uint4*)&k1f[(s * 64 + l) * 8]);
                const half8 b = __builtin_bit_cast(half8,
                    *(const uint4*)&w2h[(((size_t)c * 8 + s) * 64 + l) * 8]);
                acc = __builtin_amdgcn_mfma_f32_32x32x16_f16(a, b, acc, 0, 0, 0);
            }
            const float bb = b2[c * 32 + li];
#pragma unroll
            for (int r = 0; r < 16; r++) {
                const int e = (r & 3) + 8 * (r >> 2) + 4 * hf;
                M_s[e * 258 + c * 32 + li] = (u16)f2h(fmaxf(acc[r] + bb, 0.f));
            }
        }
    }
    __syncthreads();

    // epilogue: thread t -> edge el=t&31, col-chunk qq=t>>5 (32 cols)
    {
        const int el = t & 31, qq = t >> 5;
        const int w  = t >> 6;
        float vals[32];
#pragma unroll
        for (int c = 0; c < 16; c++) {
            const u32 hw = *(const u32*)&M_s[el * 258 + qq * 32 + c * 2];
            vals[c * 2]     = h2f((u16)hw);
            vals[c * 2 + 1] = h2f((u16)(hw >> 16));
        }
        float mx = 0.f;
#pragma unroll
        for (int u = 0; u < 32; u++) mx = fmaxf(mx, vals[u]);
        mx = fmaxf(mx, __shfl_xor(mx, 32, 64));     // combine 2 chunks in wave
        if ((t & 32) == 0) pmax_s[w][el] = mx;
        __syncthreads();
        mx = fmaxf(fmaxf(pmax_s[0][el], pmax_s[1][el]),
                   fmaxf(pmax_s[2][el], pmax_s[3][el]));
        const float sc  = mx / 255.f;
        const float inv = (mx > 0.f) ? 255.f / mx : 0.f;
        if (t < 32) k2s[e0 + el] = sc;
        u32 w8[8];
#pragma unroll
        for (int u = 0; u < 8; u++) {
            u32 q0 = (u32)fminf(rintf(vals[u * 4 + 0] * inv), 255.f);
            u32 q1 = (u32)fminf(rintf(vals[u * 4 + 1] * inv), 255.f);
            u32 q2 = (u32)fminf(rintf(vals[u * 4 + 2] * inv), 255.f);
            u32 q3 = (u32)fminf(rintf(vals[u * 4 + 3] * inv), 255.f);
            w8[u] = q0 | (q1 << 8) | (q2 << 16) | (q3 << 24);
        }
        u8* outp = k2base + (size_t)(e0 + el) * 256 + qq * 32;
        *(uint4*)outp        = make_uint4(w8[0], w8[1], w8[2], w8[3]);
        *(uint4*)(outp + 16) = make_uint4(w8[4], w8[5], w8[6], w8[7]);
    }
}

// ---------------------------------------------------------------------------
// Bvec[v][i] = sum_j b3[i*32+j] * h[v][j]   [r11-verbatim]
// ---------------------------------------------------------------------------
__global__ __launch_bounds__(256) void bvec_kernel(
    const float* __restrict__ h, const float* __restrict__ b3, float* __restrict__ bvec)
{
    int idx = blockIdx.x * 256 + threadIdx.x;
    if (idx >= NN * 32) return;
    int v = idx >> 5, i = idx & 31;
    const float* hp = &h[(size_t)v * 32];
    const float* bp = &b3[i * 32];
    float acc = 0.f;
#pragma unroll
    for (int c = 0; c < 8; c++) {
        float4 hv = *(const float4*)&hp[c * 4];
        float4 bv = *(const float4*)&bp[c * 4];
        acc += hv.x * bv.x + hv.y * bv.y + hv.z * bv.z + hv.w * bv.w;
    }
    bvec[idx] = acc;
}

// ---------------------------------------------------------------------------
// G in MFMA-B-fragment order, fp16. LDS h staging in packed fp16 + fdot2.
// Grid: (ceil(NN/128), 16).   [r11-verbatim]
// ---------------------------------------------------------------------------
__global__ __launch_bounds__(256) void g_kernel(
    const float* __restrict__ h, const float* __restrict__ w3,
    u16* __restrict__ Gg)
{
    __shared__ __align__(16) u32 h16[128 * 16];   // fp16 pairs of h, 8 KB
    const int t  = threadIdx.x;
    const int v0 = blockIdx.x * 128;

    {
        const int v = t >> 1, hh = t & 1;
        float4 a = make_float4(0.f, 0.f, 0.f, 0.f), b = a, c = a, d = a;
        if (v0 + v < NN) {
            const float* hp = &h[(size_t)(v0 + v) * 32 + hh * 16];
            a = *(const float4*)hp;       b = *(const float4*)(hp + 4);
            c = *(const float4*)(hp + 8); d = *(const float4*)(hp + 12);
        }
        uint4 o0, o1;
        o0.x = f2h(a.x) | (f2h(a.y) << 16);
        o0.y = f2h(a.z) | (f2h(a.w) << 16);
        o0.z = f2h(b.x) | (f2h(b.y) << 16);
        o0.w = f2h(b.z) | (f2h(b.w) << 16);
        o1.x = f2h(c.x) | (f2h(c.y) << 16);
        o1.y = f2h(c.z) | (f2h(c.w) << 16);
        o1.z = f2h(d.x) | (f2h(d.y) << 16);
        o1.w = f2h(d.z) | (f2h(d.w) << 16);
        *(uint4*)&h16[v * 16 + hh * 8]     = o0;
        *(uint4*)&h16[v * 16 + hh * 8 + 4] = o1;
    }
    __syncthreads();

    const int by    = blockIdx.y;        // step s, 0..15
    const int lane  = t >> 2;            // 0..63
    const int i     = lane & 31;
    const int halfk = lane >> 5;
    const int j0    = (t & 3) * 2;
    const int k0    = by * 16 + halfk * 8 + j0;

    u32 w0p[16], w1p[16];
    {
        const float* wp0 = &w3[(size_t)k0 * 1024 + (size_t)i * 32];
        const float* wp1 = wp0 + 1024;
#pragma unroll
        for (int c = 0; c < 8; c++) {
            const float4 a = *(const float4*)&wp0[c * 4];
            w0p[c * 2]     = f2h(a.x) | (f2h(a.y) << 16);
            w0p[c * 2 + 1] = f2h(a.z) | (f2h(a.w) << 16);
            const float4 b = *(const float4*)&wp1[c * 4];
            w1p[c * 2]     = f2h(b.x) | (f2h(b.y) << 16);
            w1p[c * 2 + 1] = f2h(b.z) | (f2h(b.w) << 16);
        }
    }
    const int vmax = min(128, NN - v0);
    u32* outp = (u32*)Gg;
#pragma unroll 2
    for (int v = 0; v < vmax; v++) {
        float a0 = 0.f, a1 = 0.f;
#pragma unroll
        for (int c = 0; c < 4; c++) {
            const uint4 q = *(const uint4*)&h16[v * 16 + c * 4];
            const half2t h0 = __builtin_bit_cast(half2t, q.x);
            const half2t h1 = __builtin_bit_cast(half2t, q.y);
            const half2t h2 = __builtin_bit_cast(half2t, q.z);
            const half2t h3 = __builtin_bit_cast(half2t, q.w);
            a0 = __builtin_amdgcn_fdot2(h0, __builtin_bit_cast(half2t, w0p[c*4+0]), a0, false);
            a0 = __builtin_amdgcn_fdot2(h1, __builtin_bit_cast(half2t, w0p[c*4+1]), a0, false);
            a0 = __builtin_amdgcn_fdot2(h2, __builtin_bit_cast(half2t, w0p[c*4+2]), a0, false);
            a0 = __builtin_amdgcn_fdot2(h3, __builtin_bit_cast(half2t, w0p[c*4+3]), a0, false);
            a1 = __builtin_amdgcn_fdot2(h0, __builtin_bit_cast(half2t, w1p[c*4+0]), a1, false);
            a1 = __builtin_amdgcn_fdot2(h1, __builtin_bit_cast(half2t, w1p[c*4+1]), a1, false);
            a1 = __builtin_amdgcn_fdot2(h2, __builtin_bit_cast(half2t, w1p[c*4+2]), a1, false);
            a1 = __builtin_amdgcn_fdot2(h3, __builtin_bit_cast(half2t, w1p[c*4+3]), a1, false);
        }
        outp[(size_t)(v0 + v) * 4096 + by * 256 + t] = f2h(a0) | (f2h(a1) << 16);
    }
}

// ---------------------------------------------------------------------------
// MFMA edge pass (r11-verbatim). One wave64 per col-node n.
// ---------------------------------------------------------------------------
__global__ __launch_bounds__(256) void edge_kernel(
    const int* __restrict__ cstart, const int* __restrict__ elist,
    const int* __restrict__ ridx, const int* __restrict__ rpos,
    const u8* __restrict__ k2base, const float* __restrict__ k2s,
    const u16* __restrict__ Gg, const float* __restrict__ coord,
    const u16* __restrict__ cmpk, const float* __restrict__ cm1b,
    const float* __restrict__ cm2w, const float* __restrict__ cm2b,
    const float* __restrict__ bvec,
    float* __restrict__ agg, float* __restrict__ dco,
    u16* __restrict__ mbuf, u16* __restrict__ webuf, int mode)
{
    const int t    = threadIdx.x;
    const int w    = t >> 6;
    const int l    = t & 63;
    const int li   = l & 31;
    const int half = l >> 5;

    __shared__ __align__(16) float Mlds_all[4][32 * 34];
    __shared__ int idxS_all[4][32];
    float* Mlds = Mlds_all[w];
    int*   idxS = idxS_all[w];

    const int n = blockIdx.x * 4 + w;
    if (n >= NN) return;
    const int s0  = cstart[n];
    const int deg = cstart[n + 1] - s0;
    if (deg == 0) return;

    half8 cmb[2];
    cmb[0] = __builtin_bit_cast(half8, *(const uint4*)&cmpk[(size_t)(0 * 64 + l) * 8]);
    cmb[1] = __builtin_bit_cast(half8, *(const uint4*)&cmpk[(size_t)(1 * 64 + l) * 8]);
    half8 onesb;
#pragma unroll
    for (int j = 0; j < 8; j++) onesb[j] = (_Float16)1.0f;
    const float cm1bq = cm1b[li];
    const float cm2q  = cm2w[li];
    const float cm2b0 = cm2b[0];
    const float bv    = bvec[n * 32 + li];
    const float con   = (mode == 0 && li < 3) ? coord[(size_t)n * 3 + li] : 0.f;
    const u16* Gn = Gg + (size_t)n * 8192;

    for (int base = 0; base < deg; base += 32) {
        const int mye   = base + li;
        const int valid = (mye < deg) ? 1 : 0;
        const int eid   = valid ? elist[s0 + mye] : 0;
        if (l < 32) idxS[l] = valid ? (mode ? rpos[eid] : ridx[eid]) : 0;

        uint4 gr[16];
#pragma unroll
        for (int s = 0; s < 16; s++)
            gr[s] = *(const uint4*)(Gn + s * 512 + l * 8);
        const float se = valid ? k2s[eid] : 0.f;
        const u8* k2row = k2base + (size_t)eid * 256 + half * 8;
        uint2 kr[16];
#pragma unroll
        for (int s = 0; s < 16; s++) kr[s] = *(const uint2*)(k2row + s * 16);

        floatx16 acc;
#pragma unroll
        for (int r = 0; r < 16; r++) acc[r] = bv;
#pragma unroll
        for (int s = 0; s < 16; s++) {
            half8 a;
#pragma unroll
            for (int j = 0; j < 4; j++) {
                a[j]     = (_Float16)((float)((kr[s].x >> (8 * j)) & 0xffu) * se);
                a[4 + j] = (_Float16)((float)((kr[s].y >> (8 * j)) & 0xffu) * se);
            }
            acc = __builtin_amdgcn_mfma_f32_32x32x16_f16(
                a, __builtin_bit_cast(half8, gr[s]), acc, 0, 0, 0);
        }

#pragma unroll
        for (int r = 0; r < 16; r++) {
            const int e = (r & 3) + 8 * (r >> 2) + 4 * half;
            Mlds[e * 34 + li] = acc[r];
        }
        if (mode == 0) {
#pragma unroll
            for (int r = 0; r < 16; r++) {
                const int e = (r & 3) + 8 * (r >> 2) + 4 * half;
                if (base + e < deg)
                    atomicAdd(&agg[(size_t)idxS[e] * 32 + li], acc[r]);
            }
        } else {
#pragma unroll
            for (int r = 0; r < 16; r++) {
                const int e = (r & 3) + 8 * (r >> 2) + 4 * half;
                if (base + e < deg)
                    mbuf[(size_t)idxS[e] * 32 + li] = (u16)f2h(acc[r]);
            }
        }
        asm volatile("s_waitcnt lgkmcnt(0)" ::: "memory");

        floatx16 acc2;
#pragma unroll
        for (int r = 0; r < 16; r++) acc2[r] = cm1bq;
#pragma unroll
        for (int s2 = 0; s2 < 2; s2++) {
            const float* mp = &Mlds[li * 34 + s2 * 16 + half * 8];
            const float2 m0 = *(const float2*)mp;
            const float2 m1 = *(const float2*)(mp + 2);
            const float2 m2 = *(const float2*)(mp + 4);
            const float2 m3 = *(const float2*)(mp + 6);
            half8 a;
            a[0] = (_Float16)m0.x; a[1] = (_Float16)m0.y;
            a[2] = (_Float16)m1.x; a[3] = (_Float16)m1.y;
            a[4] = (_Float16)m2.x; a[5] = (_Float16)m2.y;
            a[6] = (_Float16)m3.x; a[7] = (_Float16)m3.y;
            acc2 = __builtin_amdgcn_mfma_f32_32x32x16_f16(a, cmb[s2], acc2, 0, 0, 0);
        }

#pragma unroll
        for (int r = 0; r < 16; r++) {
            const int e = (r & 3) + 8 * (r >> 2) + 4 * half;
            Mlds[e * 34 + li] = fmaxf(acc2[r], 0.f) * cm2q;
        }
        asm volatile("s_waitcnt lgkmcnt(0)" ::: "memory");
        floatx16 acc3;
#pragma unroll
        for (int r = 0; r < 16; r++) acc3[r] = cm2b0;
#pragma unroll
        for (int s2 = 0; s2 < 2; s2++) {
            const float* mp = &Mlds[li * 34 + s2 * 16 + half * 8];
            const float2 m0 = *(const float2*)mp;
            const float2 m1 = *(const float2*)(mp + 2);
            const float2 m2 = *(const float2*)(mp + 4);
            const float2 m3 = *(const float2*)(mp + 6);
            half8 a;
            a[0] = (_Float16)m0.x; a[1] = (_Float16)m0.y;
            a[2] = (_Float16)m1.x; a[3] = (_Float16)m1.y;
            a[4] = (_Float16)m2.x; a[5] = (_Float16)m2.y;
            a[6] = (_Float16)m3.x; a[7] = (_Float16)m3.y;
            acc3 = __builtin_amdgcn_mfma_f32_32x32x16_f16(a, onesb, acc3, 0, 0, 0);
        }

        if (mode == 0) {
#pragma unroll
            for (int r = 0; r < 16; r++) {
                const int e = (r & 3) + 8 * (r >> 2) + 4 * half;
                if (base + e < deg && li < 3) {
                    const int rr = idxS[e];
                    const float d = coord[(size_t)rr * 3 + li] - con;
                    atomicAdd(&dco[(size_t)rr * 3 + li], d * acc3[r]);
                }
            }
        } else {
#pragma unroll
            for (int r = 0; r < 16; r++) {
                const int e = (r & 3) + 8 * (r >> 2) + 4 * half;
                if (base + e < deg && li == 0)
                    webuf[idxS[e]] = (u16)f2h(acc3[r]);
            }
        }
    }
}

// ---------------------------------------------------------------------------
__global__ __launch_bounds__(256) void node_update_kernel(
    float* __restrict__ h, float* __restrict__ agg,
    float* __restrict__ coord, float* __restrict__ dco,
    const float* __restrict__ invc)
{
    int idx = blockIdx.x * 256 + threadIdx.x;
    if (idx < NN * 32) {
        int v = idx >> 5;
        h[idx] = fmaxf(h[idx] + agg[idx] * invc[v], 0.f);
        agg[idx] = 0.f;
    }
    if (idx < NN * 3) {
        coord[idx] += dco[idx] * invc[idx / 3];
        dco[idx] = 0.f;
    }
}

// ---------------------------------------------------------------------------
__global__ __launch_bounds__(256) void node_update2_kernel(
    float* __restrict__ h, const float* __restrict__ coordCur,
    float* __restrict__ coordNew, const u16* __restrict__ mbuf,
    const u16* __restrict__ webuf, const int* __restrict__ rcol,
    const int* __restrict__ rstart, const float* __restrict__ invc)
{
    const int t = threadIdx.x, w = t >> 6, l = t & 63;
    const int li = l & 31, half = l >> 5;
    const int v = blockIdx.x * 4 + w;
    if (v >= NN) return;
    const int s0 = rstart[v], s1 = rstart[v + 1];
    const float iv = invc[v];

    float acc = 0.f;
    for (int s = s0 + half; s < s1; s += 2)
        acc += h2f(mbuf[(size_t)s * 32 + li]);
    acc += __shfl_xor(acc, 32, 64);
    if (half == 0)
        h[(size_t)v * 32 + li] = fmaxf(h[(size_t)v * 32 + li] + acc * iv, 0.f);

    const float c0 = coordCur[(size_t)v * 3 + 0];
    const float c1 = coordCur[(size_t)v * 3 + 1];
    const float c2 = coordCur[(size_t)v * 3 + 2];
    float p0 = 0.f, p1 = 0.f, p2 = 0.f;
    for (int s = s0 + l; s < s1; s += 64) {
        const float we = h2f(webuf[s]);
        const int col = rcol[s];
        p0 += (c0 - coordCur[(size_t)col * 3 + 0]) * we;
        p1 += (c1 - coordCur[(size_t)col * 3 + 1]) * we;
        p2 += (c2 - coordCur[(size_t)col * 3 + 2]) * we;
    }
#pragma unroll
    for (int off = 32; off >= 1; off >>= 1) {
        p0 += __shfl_xor(p0, off, 64);
        p1 += __shfl_xor(p1, off, 64);
        p2 += __shfl_xor(p2, off, 64);
    }
    if (l == 0) {
        coordNew[(size_t)v * 3 + 0] = c0 + p0 * iv;
        coordNew[(size_t)v * 3 + 1] = c1 + p1 * iv;
        coordNew[(size_t)v * 3 + 2] = c2 + p2 * iv;
    }
}

// ---------------------------------------------------------------------------
__global__ __launch_bounds__(256) void final_kernel(
    const float* __restrict__ h, const float* __restrict__ coord,
    const float* __restrict__ wa, const float* __restrict__ ba,
    const float* __restrict__ wb, const float* __restrict__ bb,
    float* __restrict__ out)
{
    const int lane = threadIdx.x & 63;
    const int v = blockIdx.x * 4 + (threadIdx.x >> 6);
    if (v >= NN) return;
    const float hreg = (lane < 32) ? h[(size_t)v * 32 + lane] : 0.f;
    float acc = ba[lane];
#pragma unroll
    for (int f = 0; f < 32; f++) acc += __shfl(hreg, f, 64) * wa[f * 64 + lane];
    float part = fmaxf(acc, 0.f) * wb[lane];
#pragma unroll
    for (int off = 32; off >= 1; off >>= 1) part += __shfl_xor(part, off, 64);
    if (lane == 0) out[v] = part + bb[0];
    if (lane < 3) out[NN + (size_t)v * 3 + lane] = coord[(size_t)v * 3 + lane];
}

// ---------------------------------------------------------------------------
extern "C" void kernel_launch(void* const* d_in, const int* in_sizes, int n_in,
                              void* d_out, int out_size, void* d_ws, size_t ws_size,
                              hipStream_t stream)
{
    const float* x    = (const float*)d_in[0];
    const int*   ei   = (const int*)d_in[1];
    const float* ea   = (const float*)d_in[2];
    const float* ci   = (const float*)d_in[3];
    const float* fc1w = (const float*)d_in[4];
    const float* fc1b = (const float*)d_in[5];
    const float* k1w  = (const float*)d_in[6];
    const float* k1b  = (const float*)d_in[7];
    const float* k2w  = (const float*)d_in[8];
    const float* k2b  = (const float*)d_in[9];
    const float* k3w  = (const float*)d_in[10];
    const float* k3b  = (const float*)d_in[11];
    const float* cm1w = (const float*)d_in[12];
    const float* cm1b = (const float*)d_in[13];
    const float* cm2w = (const float*)d_in[14];
    const float* cm2b = (const float*)d_in[15];
    const float* f2aw = (const float*)d_in[16];
    const float* f2ab = (const float*)d_in[17];
    const float* f2bw = (const float*)d_in[18];
    const float* f2bb = (const float*)d_in[19];

    size_t o_k2, o_k2s, o_G, o_h, o_bv, o_coA, o_coB, o_invc, o_rc, o_cc,
           o_cs, o_rs, o_cn, o_rn, o_el, o_w2h, o_cmpk, o_agg, o_dco,
           o_ri, o_ci, o_rp, o_rcl, o_mb, o_wb;
#define ALGN(v) (((v) + 255) & ~(size_t)255)
    auto carve = [&](int mode) -> size_t {
        size_t o = 0;
        o_k2  = o; o += ALGN((size_t)NE * 256);
        o_k2s = o; o += ALGN((size_t)NE * 4);
        o_G   = o; o += ALGN((size_t)NN * 8192 * 2);
        o_h   = o; o += ALGN((size_t)NN * 32 * 4);
        o_bv  = o; o += ALGN((size_t)NN * 32 * 4);
        o_coA = o; o += ALGN((size_t)NN * 3 * 4);
        o_invc= o; o += ALGN((size_t)NN * 4);
        o_rc  = o; o += ALGN((size_t)NN * 4);
        o_cc  = o; o += ALGN((size_t)NN * 4);
        o_cs  = o; o += ALGN((size_t)(NN + 1) * 4);
        o_cn  = o; o += ALGN((size_t)NN * 4);
        o_el  = o; o += ALGN((size_t)NE * 4);
        o_w2h = o; o += ALGN((size_t)128 * 256 * 2);
        o_cmpk= o; o += ALGN((size_t)1024 * 2);
        if (mode == 0) {
            o_agg = o; o += ALGN((size_t)NN * 32 * 4);
            o_dco = o; o += ALGN((size_t)NN * 3 * 4);
            o_ri  = o; o += ALGN((size_t)NE * 4);
            o_ci  = o; o += ALGN((size_t)NE * 4);
            o_coB = o_coA; o_rs = o_cs; o_rn = o_cn;
            o_rp = o_el; o_rcl = o_el; o_mb = o_k2; o_wb = o_k2;
        } else {
            o_coB = o; o += ALGN((size_t)NN * 3 * 4);
            o_rs  = o; o += ALGN((size_t)(NN + 1) * 4);
            o_rn  = o; o += ALGN((size_t)NN * 4);
            o_rp  = o; o += ALGN((size_t)NE * 4);
            o_rcl = o; o += ALGN((size_t)NE * 4);
            const size_t u = o;
            o_ri = u; o_ci = u + ALGN((size_t)NE * 4);
            o_mb = u; o_wb = u + ALGN((size_t)NE * 32 * 2);
            const size_t setup_sz = 2 * ALGN((size_t)NE * 4);
            const size_t layer_sz = ALGN((size_t)NE * 32 * 2) + ALGN((size_t)NE * 2);
            o += (setup_sz > layer_sz) ? setup_sz : layer_sz;
            o_agg = o_k2; o_dco = o_k2;
        }
        return o;
    };
    int mode = (ws_size >= carve(1)) ? 1 : 0;
    size_t need = carve(mode);
    if (ws_size < need) {
        sentinel_kernel<<<(NN * 4 + 255) / 256, 256, 0, stream>>>((float*)d_out, NN * 4, 1.0e6f);
        return;
    }

    char* wsb = (char*)d_ws;
    u8*    k2g   = (u8*)(wsb + o_k2);
    float* k2s   = (float*)(wsb + o_k2s);
    u16*   Gg    = (u16*)(wsb + o_G);
    float* h     = (float*)(wsb + o_h);
    float* bvec  = (float*)(wsb + o_bv);
    float* coA   = (float*)(wsb + o_coA);
    float* coB   = (float*)(wsb + o_coB);
    float* invc  = (float*)(wsb + o_invc);
    int*   rowcnt= (int*)(wsb + o_rc);
    int*   colcnt= (int*)(wsb + o_cc);
    int*   cstart= (int*)(wsb + o_cs);
    int*   rstart= (int*)(wsb + o_rs);
    int*   cnext = (int*)(wsb + o_cn);
    int*   rnext = (int*)(wsb + o_rn);
    int*   elist = (int*)(wsb + o_el);
    u16*   w2h   = (u16*)(wsb + o_w2h);
    u16*   cmpk  = (u16*)(wsb + o_cmpk);
    float* agg   = (float*)(wsb + o_agg);
    float* dco   = (float*)(wsb + o_dco);
    int*   ridx  = (int*)(wsb + o_ri);
    int*   cidx  = (int*)(wsb + o_ci);
    int*   rpos  = (int*)(wsb + o_rp);
    int*   rcol  = (int*)(wsb + o_rcl);
    u16*   mbuf  = (u16*)(wsb + o_mb);
    u16*   webuf = (u16*)(wsb + o_wb);

    hipMemsetAsync(rowcnt, 0, (size_t)NN * 4, stream);
    hipMemsetAsync(colcnt, 0, (size_t)NN * 4, stream);
    if (mode == 0) {
        hipMemsetAsync(agg, 0, (size_t)NN * 32 * 4, stream);
        hipMemsetAsync(dco, 0, (size_t)NN * 3 * 4, stream);
    }

    detect_idx_kernel<<<1, 256, 0, stream>>>(ei, cnext);
    convert_idx_kernel<<<(2 * NE + 255) / 256, 256, 0, stream>>>(ei, cnext, ridx, cidx);
    init_nodes_kernel<<<(NN * 32 + 255) / 256, 256, 0, stream>>>(x, fc1w, fc1b, ci, h, coA);
    count_kernel<<<(NE + 255) / 256, 256, 0, stream>>>(ridx, cidx, rowcnt, colcnt);
    scan_kernel<<<1, 256, 0, stream>>>(colcnt, rowcnt, cstart, cnext, rstart, rnext,
                                       invc, mode);
    scatter_kernel<<<(NE + 255) / 256, 256, 0, stream>>>(cidx, ridx, cnext, rnext,
                                                         elist, rpos, rcol, mode);
    w2pack_kernel<<<16, 256, 0, stream>>>(k2w, w2h);
    cm1pack_kernel<<<1, 128, 0, stream>>>(cm1w, cmpk);
    mlp_k2_kernel<<<NE / 32, 256, 0, stream>>>(ea, k1w, k1b, w2h, k2b, k2g, k2s);

    float* coCur = coA;
    float* coAlt = coB;
    const dim3 ggrid((NN + 127) / 128, 16);
    for (int l = 0; l < DEPTH; l++) {
        bvec_kernel<<<(NN * 32 + 255) / 256, 256, 0, stream>>>(h, k3b, bvec);
        g_kernel<<<ggrid, 256, 0, stream>>>(h, k3w, Gg);
        edge_kernel<<<(NN + 3) / 4, 256, 0, stream>>>(cstart, elist, ridx, rpos,
                                                      k2g, k2s, Gg, coCur, cmpk,
                                                      cm1b, cm2w, cm2b, bvec,
                                                      agg, dco, mbuf, webuf, mode);
        if (mode == 1) {
            node_update2_kernel<<<(NN + 3) / 4, 256, 0, stream>>>(
                h, coCur, coAlt, mbuf, webuf, rcol, rstart, invc);
            float* tmp = coCur; coCur = coAlt; coAlt = tmp;
        } else {
            node_update_kernel<<<(NN * 32 + 255) / 256, 256, 0, stream>>>(
                h, agg, coCur, dco, invc);
        }
    }
    final_kernel<<<(NN + 3) / 4, 256, 0, stream>>>(h, coCur, f2aw, f2ab, f2bw, f2bb,
                                                   (float*)d_out);
}